// Round 7
// baseline (192.069 us; speedup 1.0000x reference)
//
#include <hip/hip_runtime.h>
#include <hip/hip_bf16.h>
#include <math.h>

typedef unsigned short u16;
typedef __attribute__((ext_vector_type(8))) short bf16x8;
typedef __attribute__((ext_vector_type(16))) float f32x16;

constexpr int D_ = 1024;
constexpr int H_ = 1365;
constexpr int E_ = 7;
constexpr int NTOK = 2048;
constexpr int HP = 1408;          // H padded to multiple of 64
constexpr int NE = 8;             // 7 routed + 1 shared
constexpr int SHARED_BASE = 4096;
constexpr int SLOTS = 6144;

#define CI_COUNT 0
#define CI_OFF   8

constexpr size_t WS_CTRL = 0;
constexpr size_t WS_TIDX = 256;
constexpr size_t WS_TW   = WS_TIDX + (size_t)NTOK*2*4;
constexpr size_t WS_PROB = WS_TW   + (size_t)NTOK*2*4;
constexpr size_t WS_LSE2 = WS_PROB + (size_t)NTOK*8*4;
constexpr size_t WS_STOK = WS_LSE2 + (size_t)NTOK*4;
constexpr size_t WS_SW   = WS_STOK + (size_t)SLOTS*4;
constexpr size_t WS_B1   = WS_SW   + (size_t)SLOTS*4;
constexpr size_t WS_B2   = WS_B1   + (size_t)NE*H_*4;
constexpr size_t WS_XB   = ((WS_B2 + (size_t)NE*D_*4) + 255) & ~(size_t)255;
constexpr size_t WS_W1B  = WS_XB  + (size_t)NTOK*D_*2;
constexpr size_t WS_W2B  = WS_W1B + (size_t)NE*H_*D_*2;
constexpr size_t WS_HEB  = WS_W2B + (size_t)NE*D_*HP*2;

__device__ __forceinline__ u16 f2bf(float f) {
    __hip_bfloat16 h = __float2bfloat16(f);
    return __builtin_bit_cast(u16, h);
}

__device__ __forceinline__ void gload_lds16(const u16* g, u16* l) {
    __builtin_amdgcn_global_load_lds(
        (const __attribute__((address_space(1))) void*)g,
        (__attribute__((address_space(3))) void*)l, 16, 0, 0);
}

__device__ __forceinline__ uint4 pack8(float4 a, float4 b) {
    union { u16 h[8]; uint4 v; } u;
    u.h[0]=f2bf(a.x); u.h[1]=f2bf(a.y); u.h[2]=f2bf(a.z); u.h[3]=f2bf(a.w);
    u.h[4]=f2bf(b.x); u.h[5]=f2bf(b.y); u.h[6]=f2bf(b.z); u.h[7]=f2bf(b.w);
    return u.v;
}

// tanh-form GELU (|err| ~3e-3, below bf16 quantization of He)
__device__ __forceinline__ float fast_gelu(float v) {
    float u = 0.7978845608f * v * (1.f + 0.044715f * v * v);
    float e = __expf(2.f * u);
    float t = 1.f - 2.f / (e + 1.f);
    return 0.5f * v * (1.f + t);
}

// ========== GEMM core: 128x128 block, BK=64, 4 waves of 64x64, mfma 32x32x16 ==========
#define BM 128
#define BN 128
#define KSTEP 64
#define ATILE (BM*KSTEP)    // 8192 elems = 16 KiB
#define BTILE (BN*KSTEP)    // 16 KiB
// LDS: 2 buffers * (16+16) KiB = 64 KiB -> 2 blocks/CU

#define MFMA32(a,b,c) __builtin_amdgcn_mfma_f32_32x32x16_bf16(a, b, c, 0, 0, 0)

// He = gelu(X @ W1e^T + b1e): A rows gathered via stok (or identity for shared)
template<bool USE_STOK>
__device__ __forceinline__ void gemm1_body(u16* As, u16* Bs,
    const u16* xb, const u16* w1e, const float* b1e,
    const int* stok, int offset, int m0, int valid, int nt,
    u16* heb)
{
    int t = threadIdx.x, wid = t >> 6, lane = t & 63;
    int rl = lane >> 3, cl = lane & 7;
    int sg = cl ^ rl;                    // pre-swizzled 16B-chunk (involution, 128B rows)

    const u16* aP[4]; const u16* bP[4]; int dOff[4];
    #pragma unroll
    for (int c = 0; c < 4; c++) {
        int row = wid*32 + c*8 + rl;
        int ar = min(row, valid-1);
        int tok = USE_STOK ? stok[offset + m0 + ar] : (m0 + ar);
        aP[c] = xb + (size_t)tok*D_ + sg*8;
        int jg = min(nt*BN + row, H_-1);
        bP[c] = w1e + (size_t)jg*D_ + sg*8;
        dOff[c] = (wid*32 + c*8)*KSTEP;
    }

    int wm = (wid >> 1)*64, wn = (wid & 1)*64;
    int fr = lane & 31, hi = lane >> 5, f7 = lane & 7;
    f32x16 acc[2][2] = {};

    #pragma unroll
    for (int c = 0; c < 4; c++) {        // prologue: stage tile 0 into buf 0
        gload_lds16(aP[c], As + dOff[c]);
        gload_lds16(bP[c], Bs + dOff[c]);
    }
    constexpr int nIter = D_/KSTEP;      // 16
    int cur = 0;
    for (int tt = 0; tt < nIter; ++tt) {
        if (tt + 1 < nIter) {
            int bo2 = (cur^1)*ATILE;
            int ko = (tt+1)*KSTEP;
            #pragma unroll
            for (int c = 0; c < 4; c++) {
                gload_lds16(aP[c]+ko, As + bo2 + dOff[c]);
                gload_lds16(bP[c]+ko, Bs + bo2 + dOff[c]);
            }
            asm volatile("s_waitcnt vmcnt(8)" ::: "memory");
        } else {
            asm volatile("s_waitcnt vmcnt(0)" ::: "memory");
        }
        __builtin_amdgcn_s_barrier();
        __builtin_amdgcn_sched_barrier(0);
        const u16* ab = As + cur*ATILE;
        const u16* bb = Bs + cur*ATILE;
        __builtin_amdgcn_s_setprio(1);
        #pragma unroll
        for (int ks = 0; ks < 4; ks++) {
            int ch = ((ks*2 + hi) ^ f7) * 8;
            bf16x8 a0 = *(const bf16x8*)&ab[(wm +      fr)*KSTEP + ch];
            bf16x8 a1 = *(const bf16x8*)&ab[(wm + 32 + fr)*KSTEP + ch];
            bf16x8 b0 = *(const bf16x8*)&bb[(wn +      fr)*KSTEP + ch];
            bf16x8 b1 = *(const bf16x8*)&bb[(wn + 32 + fr)*KSTEP + ch];
            acc[0][0] = MFMA32(a0, b0, acc[0][0]);
            acc[0][1] = MFMA32(a0, b1, acc[0][1]);
            acc[1][0] = MFMA32(a1, b0, acc[1][0]);
            acc[1][1] = MFMA32(a1, b1, acc[1][1]);
        }
        __builtin_amdgcn_s_setprio(0);
        asm volatile("s_waitcnt lgkmcnt(0)" ::: "memory");
        __builtin_amdgcn_sched_barrier(0);
        __builtin_amdgcn_s_barrier();
        cur ^= 1;
    }

    // C/D: col = lane&31, row = (reg&3) + 8*(reg>>2) + 4*(lane>>5)  [m74/m101]
    #pragma unroll
    for (int mf = 0; mf < 2; mf++) {
        #pragma unroll
        for (int r = 0; r < 16; r++) {
            int row = wm + mf*32 + (r & 3) + 8*(r >> 2) + 4*hi;
            if (row < valid) {
                size_t rbase = (size_t)(offset + m0 + row)*HP;
                #pragma unroll
                for (int nf = 0; nf < 2; nf++) {
                    int gcol = nt*BN + wn + nf*32 + fr;
                    float v = 0.f;
                    if (gcol < H_) v = fast_gelu(acc[mf][nf][r] + b1e[gcol]);
                    heb[rbase + gcol] = f2bf(v);
                }
            }
        }
    }
}

// out += w * (He @ W2e^T + b2e).  MODE 0: plain store (shared, w=1); MODE 1: atomicAdd
template<int MODE>
__device__ __forceinline__ void gemm2_body(u16* As, u16* Bs,
    const u16* heb, const u16* w2e, const float* b2e, const float* sw,
    int offset, int m0, int valid, int nt, float* out, const int* stok)
{
    int t = threadIdx.x, wid = t >> 6, lane = t & 63;
    int rl = lane >> 3, cl = lane & 7;
    int sg = cl ^ rl;

    const u16* aP[4]; const u16* bP[4]; int dOff[4];
    #pragma unroll
    for (int c = 0; c < 4; c++) {
        int row = wid*32 + c*8 + rl;
        int ar = min(row, valid-1);
        aP[c] = heb + (size_t)(offset + m0 + ar)*HP + sg*8;
        int jg = nt*BN + row;             // < 1024 always
        bP[c] = w2e + (size_t)jg*HP + sg*8;
        dOff[c] = (wid*32 + c*8)*KSTEP;
    }

    int wm = (wid >> 1)*64, wn = (wid & 1)*64;
    int fr = lane & 31, hi = lane >> 5, f7 = lane & 7;
    f32x16 acc[2][2] = {};

    #pragma unroll
    for (int c = 0; c < 4; c++) {
        gload_lds16(aP[c], As + dOff[c]);
        gload_lds16(bP[c], Bs + dOff[c]);
    }
    constexpr int nIter = HP/KSTEP;      // 22
    int cur = 0;
    for (int tt = 0; tt < nIter; ++tt) {
        if (tt + 1 < nIter) {
            int bo2 = (cur^1)*ATILE;
            int ko = (tt+1)*KSTEP;
            #pragma unroll
            for (int c = 0; c < 4; c++) {
                gload_lds16(aP[c]+ko, As + bo2 + dOff[c]);
                gload_lds16(bP[c]+ko, Bs + bo2 + dOff[c]);
            }
            asm volatile("s_waitcnt vmcnt(8)" ::: "memory");
        } else {
            asm volatile("s_waitcnt vmcnt(0)" ::: "memory");
        }
        __builtin_amdgcn_s_barrier();
        __builtin_amdgcn_sched_barrier(0);
        const u16* ab = As + cur*ATILE;
        const u16* bb = Bs + cur*ATILE;
        __builtin_amdgcn_s_setprio(1);
        #pragma unroll
        for (int ks = 0; ks < 4; ks++) {
            int ch = ((ks*2 + hi) ^ f7) * 8;
            bf16x8 a0 = *(const bf16x8*)&ab[(wm +      fr)*KSTEP + ch];
            bf16x8 a1 = *(const bf16x8*)&ab[(wm + 32 + fr)*KSTEP + ch];
            bf16x8 b0 = *(const bf16x8*)&bb[(wn +      fr)*KSTEP + ch];
            bf16x8 b1 = *(const bf16x8*)&bb[(wn + 32 + fr)*KSTEP + ch];
            acc[0][0] = MFMA32(a0, b0, acc[0][0]);
            acc[0][1] = MFMA32(a0, b1, acc[0][1]);
            acc[1][0] = MFMA32(a1, b0, acc[1][0]);
            acc[1][1] = MFMA32(a1, b1, acc[1][1]);
        }
        __builtin_amdgcn_s_setprio(0);
        asm volatile("s_waitcnt lgkmcnt(0)" ::: "memory");
        __builtin_amdgcn_sched_barrier(0);
        __builtin_amdgcn_s_barrier();
        cur ^= 1;
    }

    #pragma unroll
    for (int mf = 0; mf < 2; mf++) {
        #pragma unroll
        for (int r = 0; r < 16; r++) {
            int row = wm + mf*32 + (r & 3) + 8*(r >> 2) + 4*hi;
            if (row < valid) {
                if (MODE == 0) {
                    float* orow = out + (size_t)(m0 + row)*D_;
                    #pragma unroll
                    for (int nf = 0; nf < 2; nf++) {
                        int gcol = nt*BN + wn + nf*32 + fr;
                        orow[gcol] = acc[mf][nf][r] + b2e[gcol];
                    }
                } else {
                    int slot = offset + m0 + row;
                    int tok = stok[slot];
                    float w = sw[slot];
                    #pragma unroll
                    for (int nf = 0; nf < 2; nf++) {
                        int gcol = nt*BN + wn + nf*32 + fr;
                        atomicAdd(out + (size_t)tok*D_ + gcol, w*(acc[mf][nf][r] + b2e[gcol]));
                    }
                }
            }
        }
    }
}

// ================= finalize (256 threads): counts, offsets, losses, scatter =================
__device__ void finalize_body(char* smem,
    const int* tidx, const float* tw, const float* probs, const float* lse2,
    int* ci, int* stok, float* sw, float* out)
{
    int*   lt   = (int*)smem;               // 4096 ints (16 KiB)
    float* psum = (float*)(smem + 16384);
    float* lsum = (float*)(smem + 16384 + 32);
    int*   cntS = (int*)(smem + 16448);
    int*   offS = (int*)(smem + 16480);
    int t = threadIdx.x;
    if (t < 8) { psum[t] = 0.f; cntS[t] = 0; }
    if (t == 0) *lsum = 0.f;
    for (int i = t; i < NTOK*2; i += 256) lt[i] = tidx[i];
    for (int n = t; n < NTOK; n += 256) { stok[SHARED_BASE+n] = n; sw[SHARED_BASE+n] = 1.f; }
    __syncthreads();
    float lp[E_] = {}; float ll = 0.f;
    for (int n = t; n < NTOK; n += 256) {
        #pragma unroll
        for (int e = 0; e < E_; e++) lp[e] += probs[n*8+e];
        ll += lse2[n];
    }
    #pragma unroll
    for (int e = 0; e < E_; e++) atomicAdd(&psum[e], lp[e]);
    atomicAdd(lsum, ll);
    int wid = t >> 6, lane = t & 63;
    for (int e = wid; e < 7; e += 4) {
        int c = 0;
        for (int i = lane; i < NTOK*2; i += 64) c += (lt[i] == e) ? 1 : 0;
        #pragma unroll
        for (int m = 32; m >= 1; m >>= 1) c += __shfl_xor(c, m);
        if (lane == 0) cntS[e] = c;
    }
    __syncthreads();
    if (t == 0) {
        int o = 0;
        for (int e = 0; e < E_; e++) { offS[e] = o; o += cntS[e]; }
        offS[7] = SHARED_BASE; cntS[7] = NTOK;
        float la = 0.f;
        for (int e = 0; e < E_; e++)
            la += ((float)cntS[e] / (float)(NTOK*2)) * (psum[e] / (float)NTOK);
        out[(size_t)NTOK*D_]     = 0.01f * 7.f * la;
        out[(size_t)NTOK*D_ + 1] = 0.001f * (*lsum) / (float)NTOK;
        #pragma unroll
        for (int e = 0; e < 8; e++) { ci[CI_COUNT+e] = cntS[e]; ci[CI_OFF+e] = offS[e]; }
    }
    __syncthreads();
    for (int e = wid; e < 7; e += 4) {
        int base = offS[e], run = 0;
        for (int c0 = 0; c0 < NTOK*2; c0 += 64) {
            bool m = (lt[c0 + lane] == e);
            unsigned long long bal = __ballot(m);
            int pre = __popcll(bal & ((1ull << lane) - 1ull));
            if (m) {
                int i = c0 + lane;
                int s = base + run + pre;
                stok[s] = i >> 1; sw[s] = tw[i];
            }
            run += __popcll(bal);
        }
    }
}

// ==== k1: router (0..511) || ALL weight converts (512..1535) — NO LDS, full occupancy ====
__global__ void prep_kernel(
    const float* __restrict__ x, const float* __restrict__ Wg,
    const float* __restrict__ W1, const float* __restrict__ Ws1,
    const float* __restrict__ W2, const float* __restrict__ Ws2,
    const float* __restrict__ b1, const float* __restrict__ bs1,
    const float* __restrict__ b2, const float* __restrict__ bs2,
    int* __restrict__ tidx, float* __restrict__ tw,
    float* __restrict__ probs, float* __restrict__ lse2,
    u16* __restrict__ xb, u16* __restrict__ w1b, u16* __restrict__ w2b,
    float* __restrict__ b1all, float* __restrict__ b2all)
{
    int b = blockIdx.x;
    if (b < 512) {
        int wid = threadIdx.x >> 6, lane = threadIdx.x & 63;
        int n = b*4 + wid;
        float p[E_] = {};
        const float* xr = x + (size_t)n*D_;
        u16* xbr = xb + (size_t)n*D_;
        #pragma unroll
        for (int j = 0; j < 4; j++) {
            int d0 = lane*4 + j*256;
            float4 xv = *(const float4*)(xr + d0);
            ushort4 h;
            h.x = f2bf(xv.x); h.y = f2bf(xv.y); h.z = f2bf(xv.z); h.w = f2bf(xv.w);
            *(ushort4*)(xbr + d0) = h;
            #pragma unroll
            for (int e = 0; e < E_; e++) {
                float4 wv = *(const float4*)(Wg + e*D_ + d0);
                p[e] += xv.x*wv.x + xv.y*wv.y + xv.z*wv.z + xv.w*wv.w;
            }
        }
        #pragma unroll
        for (int e = 0; e < E_; e++) {
            float v = p[e];
            #pragma unroll
            for (int m = 32; m >= 1; m >>= 1) v += __shfl_xor(v, m);
            p[e] = v;
        }
        if (lane == 0) {
            float mx = p[0];
            #pragma unroll
            for (int e = 1; e < E_; e++) mx = fmaxf(mx, p[e]);
            float pr[E_], sum = 0.f;
            #pragma unroll
            for (int e = 0; e < E_; e++) { pr[e] = __expf(p[e]-mx); sum += pr[e]; }
            float lse = mx + logf(sum);
            int i0 = 0;
            #pragma unroll
            for (int e = 1; e < E_; e++) if (p[e] > p[i0]) i0 = e;
            int i1 = -1;
            #pragma unroll
            for (int e = 0; e < E_; e++) if (e != i0 && (i1 < 0 || p[e] > p[i1])) i1 = e;
            float g = expf(p[i1] - p[i0]);
            tidx[n*2] = i0; tidx[n*2+1] = i1;
            tw[n*2] = 1.f/(1.f+g); tw[n*2+1] = g/(1.f+g);
            float inv = 1.f/sum;
            #pragma unroll
            for (int e = 0; e < E_; e++) probs[n*8+e] = pr[e]*inv;
            lse2[n] = lse*lse;
        }
        return;
    }
    // ---- converts: W1 | W2 | b1 | b2 ----
    const size_t G1 = (size_t)NE*H_*D_/8;
    const size_t G2 = (size_t)NE*D_*HP/8;
    const size_t W1FLAT = (size_t)7*H_*D_;
    const size_t total = G1 + G2 + (size_t)NE*H_ + (size_t)NE*D_;
    const size_t stride = (size_t)1024*256;
    for (size_t i = (size_t)(b-512)*256 + threadIdx.x; i < total; i += stride) {
        size_t k = i;
        if (k < G1) {
            size_t base = k*8;
            const float* src = (base < W1FLAT) ? (W1 + base) : (Ws1 + (base - W1FLAT));
            const float4* s = (const float4*)src;
            ((uint4*)w1b)[k] = pack8(s[0], s[1]);
            continue;
        }
        k -= G1;
        if (k < G2) {
            size_t base = k*8;
            size_t e = base/((size_t)D_*HP);
            size_t rr = base - e*(size_t)D_*HP;
            size_t drow = rr/HP, h0 = rr - drow*HP;
            const float* srow = (e < 7) ? (W2 + ((size_t)e*D_ + drow)*H_)
                                        : (Ws2 + drow*(size_t)H_);
            union { u16 h[8]; uint4 v; } u;
            #pragma unroll
            for (int q = 0; q < 8; q++) {
                size_t h = h0 + q;
                u.h[q] = (h < (size_t)H_) ? f2bf(srow[h]) : (u16)0;
            }
            ((uint4*)w2b)[k] = u.v;
            continue;
        }
        k -= G2;
        if (k < (size_t)NE*H_) {
            size_t e = k/H_, j = k - e*H_;
            b1all[k] = (e < 7) ? b1[k] : bs1[j];
        } else {
            size_t kk = k - (size_t)NE*H_;
            size_t e = kk/D_, j = kk - e*D_;
            b2all[kk] = (e < 7) ? b2[kk] : bs2[j];
        }
    }
}

// ===== k2: finalize (block 0) || shared-expert GEMM1 (1..176) =====
__global__ __launch_bounds__(256, 2) void k2_kernel(
    const int* __restrict__ tidx, const float* __restrict__ tw,
    const float* __restrict__ probs, const float* __restrict__ lse2,
    int* __restrict__ ci, int* __restrict__ stok, float* __restrict__ sw,
    float* __restrict__ out,
    const u16* __restrict__ xb, const u16* __restrict__ w1b,
    const float* __restrict__ b1all, u16* __restrict__ heb)
{
    __shared__ u16 As[2*ATILE];
    __shared__ u16 Bs[2*ATILE];
    int b = blockIdx.x;
    if (b == 0) {
        finalize_body((char*)As, tidx, tw, probs, lse2, ci, stok, sw, out);
        return;
    }
    int tdx = b - 1;
    int mt = tdx/11, nt = tdx - mt*11;
    gemm1_body<false>(As, Bs, xb, w1b + (size_t)7*H_*D_, b1all + 7*H_,
                      nullptr, SHARED_BASE, mt*BM, BM, nt, heb);
}

// ===== k3: routed GEMM1 (XCD-pinned, yb<176) || shared GEMM2 (yb>=176) =====
__global__ __launch_bounds__(256, 2) void k3_kernel(
    const int* __restrict__ ci, const int* __restrict__ stok,
    const u16* __restrict__ xb, const u16* __restrict__ w1b,
    const float* __restrict__ b1all, u16* __restrict__ heb,
    const u16* __restrict__ w2b, const float* __restrict__ b2all,
    float* __restrict__ out)
{
    __shared__ u16 As[2*ATILE];
    __shared__ u16 Bs[2*ATILE];
    int x = blockIdx.x, yb = blockIdx.y;
    if (yb < 176) {
        if (x == 7) return;
        int e = x, mt = yb/11, nt = yb - mt*11;
        int count = ci[CI_COUNT+e];
        int m0 = mt*BM;
        if (m0 >= count) return;
        gemm1_body<true>(As, Bs, xb, w1b + (size_t)e*H_*D_, b1all + e*H_,
                         stok, ci[CI_OFF+e], m0, min(BM, count-m0), nt, heb);
    } else {
        int idx = (yb - 176)*8 + x;       // 0..127
        int mt = idx >> 3, nt = idx & 7;
        gemm2_body<0>(As, Bs, heb, w2b + (size_t)7*D_*HP, b2all + 7*D_,
                      nullptr, SHARED_BASE, mt*BM, BM, nt, out, nullptr);
    }
}

// ===== k4: routed GEMM2 (XCD-pinned), atomicAdd into out =====
__global__ __launch_bounds__(256, 2) void k4_kernel(
    const int* __restrict__ ci, const int* __restrict__ stok, const float* __restrict__ sw,
    const u16* __restrict__ heb, const u16* __restrict__ w2b,
    const float* __restrict__ b2all, float* __restrict__ out)
{
    __shared__ u16 As[2*ATILE];
    __shared__ u16 Bs[2*ATILE];
    int x = blockIdx.x;
    if (x == 7) return;
    int yb = blockIdx.y;
    int e = x, mt = yb >> 3, nt = yb & 7;
    int count = ci[CI_COUNT+e];
    int m0 = mt*BM;
    if (m0 >= count) return;
    gemm2_body<1>(As, Bs, heb, w2b + (size_t)e*D_*HP, b2all + e*D_,
                  sw, ci[CI_OFF+e], m0, min(BM, count-m0), nt, out, stok);
}

extern "C" void kernel_launch(void* const* d_in, const int* in_sizes, int n_in,
                              void* d_out, int out_size, void* d_ws, size_t ws_size,
                              hipStream_t stream)
{
    const float* x   = (const float*)d_in[0];
    const float* Wg  = (const float*)d_in[1];
    const float* W1  = (const float*)d_in[2];
    const float* b1  = (const float*)d_in[3];
    const float* W2  = (const float*)d_in[4];
    const float* b2  = (const float*)d_in[5];
    const float* Ws1 = (const float*)d_in[6];
    const float* bs1 = (const float*)d_in[7];
    const float* Ws2 = (const float*)d_in[8];
    const float* bs2 = (const float*)d_in[9];
    float* out = (float*)d_out;
    char* ws = (char*)d_ws;

    int*   ci    = (int*)(ws + WS_CTRL);
    int*   tidx  = (int*)(ws + WS_TIDX);
    float* tw    = (float*)(ws + WS_TW);
    float* probs = (float*)(ws + WS_PROB);
    float* lse2  = (float*)(ws + WS_LSE2);
    int*   stok  = (int*)(ws + WS_STOK);
    float* sw    = (float*)(ws + WS_SW);
    float* b1all = (float*)(ws + WS_B1);
    float* b2all = (float*)(ws + WS_B2);
    u16*   xb    = (u16*)(ws + WS_XB);
    u16*   w1b   = (u16*)(ws + WS_W1B);
    u16*   w2b   = (u16*)(ws + WS_W2B);
    u16*   heb   = (u16*)(ws + WS_HEB);

    // k1: router (512) || W1+W2+bias converts (1024) — zero LDS, full occupancy
    prep_kernel<<<1536, 256, 0, stream>>>(x, Wg, W1, Ws1, W2, Ws2, b1, bs1, b2, bs2,
                                          tidx, tw, probs, lse2, xb, w1b, w2b, b1all, b2all);
    // k2: finalize || shared-expert GEMM1 (16mt x 11nt)
    k2_kernel<<<177, 256, 0, stream>>>(tidx, tw, probs, lse2, ci, stok, sw, out,
                                       xb, w1b, b1all, heb);
    // k3: routed GEMM1 (expert->XCD pinned) || shared GEMM2
    k3_kernel<<<dim3(8, 176 + 16), 256, 0, stream>>>(ci, stok, xb, w1b, b1all, heb,
                                                     w2b, b2all, out);
    // k4: routed GEMM2, weighted atomic accumulate
    k4_kernel<<<dim3(8, 128), 256, 0, stream>>>(ci, stok, sw, heb, w2b, b2all, out);
}

// Round 8
// 163.032 us; speedup vs baseline: 1.1781x; 1.1781x over previous
//
#include <hip/hip_runtime.h>
#include <hip/hip_bf16.h>
#include <math.h>

typedef unsigned short u16;
typedef __attribute__((ext_vector_type(8))) short bf16x8;
typedef __attribute__((ext_vector_type(16))) float f32x16;

constexpr int D_ = 1024;
constexpr int H_ = 1365;
constexpr int E_ = 7;
constexpr int NTOK = 2048;
constexpr int HP = 1408;          // H padded to multiple of 64
constexpr int NE = 8;             // 7 routed + 1 shared
constexpr int SHARED_BASE = 4096;
constexpr int SLOTS = 6144;

#define CI_COUNT 0
#define CI_OFF   8

constexpr size_t WS_CTRL = 0;
constexpr size_t WS_TIDX = 256;
constexpr size_t WS_TW   = WS_TIDX + (size_t)NTOK*2*4;
constexpr size_t WS_PROB = WS_TW   + (size_t)NTOK*2*4;
constexpr size_t WS_LSE2 = WS_PROB + (size_t)NTOK*8*4;
constexpr size_t WS_STOK = WS_LSE2 + (size_t)NTOK*4;
constexpr size_t WS_SW   = WS_STOK + (size_t)SLOTS*4;
constexpr size_t WS_B1   = WS_SW   + (size_t)SLOTS*4;
constexpr size_t WS_B2   = WS_B1   + (size_t)NE*H_*4;
constexpr size_t WS_XB   = ((WS_B2 + (size_t)NE*D_*4) + 255) & ~(size_t)255;
constexpr size_t WS_W1B  = WS_XB  + (size_t)NTOK*D_*2;
constexpr size_t WS_W2B  = WS_W1B + (size_t)NE*H_*D_*2;
constexpr size_t WS_HEB  = WS_W2B + (size_t)NE*D_*HP*2;

__device__ __forceinline__ u16 f2bf(float f) {
    __hip_bfloat16 h = __float2bfloat16(f);
    return __builtin_bit_cast(u16, h);
}

__device__ __forceinline__ void gload_lds16(const u16* g, u16* l) {
    __builtin_amdgcn_global_load_lds(
        (const __attribute__((address_space(1))) void*)g,
        (__attribute__((address_space(3))) void*)l, 16, 0, 0);
}

__device__ __forceinline__ uint4 pack8(float4 a, float4 b) {
    union { u16 h[8]; uint4 v; } u;
    u.h[0]=f2bf(a.x); u.h[1]=f2bf(a.y); u.h[2]=f2bf(a.z); u.h[3]=f2bf(a.w);
    u.h[4]=f2bf(b.x); u.h[5]=f2bf(b.y); u.h[6]=f2bf(b.z); u.h[7]=f2bf(b.w);
    return u.v;
}

// tanh-form GELU (|err| ~3e-3, below bf16 quantization of He)
__device__ __forceinline__ float fast_gelu(float v) {
    float u = 0.7978845608f * v * (1.f + 0.044715f * v * v);
    float e = __expf(2.f * u);
    float t = 1.f - 2.f / (e + 1.f);
    return 0.5f * v * (1.f + t);
}

// ===== GEMM core: 128x128 block, BK=64, 512 thr / 8 waves of 64x32, mfma 32x32x16 =====
#define BM 128
#define BN 128
#define KSTEP 64
#define ATILE (BM*KSTEP)    // 8192 elems = 16 KiB
// LDS: 2 buffers * (16+16) KiB = 64 KiB -> 2 blocks/CU, 16 waves/CU (4/SIMD)

#define MFMA32(a,b,c) __builtin_amdgcn_mfma_f32_32x32x16_bf16(a, b, c, 0, 0, 0)

template<bool USE_STOK>
__device__ __forceinline__ void gemm1_body(u16* As, u16* Bs,
    const u16* xb, const u16* w1e, const float* b1e,
    const int* stok, int offset, int m0, int valid, int nt,
    u16* heb)
{
    int t = threadIdx.x, wid = t >> 6, lane = t & 63;
    int rl = lane >> 3, cl = lane & 7;
    int sg = cl ^ rl;                    // pre-swizzled 16B-chunk (involution on row&7)

    const u16* aP[2]; const u16* bP[2]; int dOff[2];
    #pragma unroll
    for (int c = 0; c < 2; c++) {
        int row = wid*16 + c*8 + rl;
        int ar = min(row, valid-1);
        int tok = USE_STOK ? stok[offset + m0 + ar] : (m0 + ar);
        aP[c] = xb + (size_t)tok*D_ + sg*8;
        int jg = min(nt*BN + row, H_-1);
        bP[c] = w1e + (size_t)jg*D_ + sg*8;
        dOff[c] = (wid*16 + c*8)*KSTEP;
    }

    int wm = (wid >> 2)*64, wn = (wid & 3)*32;
    int fr = lane & 31, hi = lane >> 5, f7 = lane & 7;
    f32x16 acc[2] = {};

    #pragma unroll
    for (int c = 0; c < 2; c++) {        // prologue: stage tile 0 into buf 0
        gload_lds16(aP[c], As + dOff[c]);
        gload_lds16(bP[c], Bs + dOff[c]);
    }
    constexpr int nIter = D_/KSTEP;      // 16
    int cur = 0;
    for (int tt = 0; tt < nIter; ++tt) {
        if (tt + 1 < nIter) {
            int bo2 = (cur^1)*ATILE;
            int ko = (tt+1)*KSTEP;
            #pragma unroll
            for (int c = 0; c < 2; c++) {
                gload_lds16(aP[c]+ko, As + bo2 + dOff[c]);
                gload_lds16(bP[c]+ko, Bs + bo2 + dOff[c]);
            }
            asm volatile("s_waitcnt vmcnt(4)" ::: "memory");
        } else {
            asm volatile("s_waitcnt vmcnt(0)" ::: "memory");
        }
        __builtin_amdgcn_s_barrier();
        __builtin_amdgcn_sched_barrier(0);
        const u16* ab = As + cur*ATILE;
        const u16* bb = Bs + cur*ATILE;
        __builtin_amdgcn_s_setprio(1);
        #pragma unroll
        for (int ks = 0; ks < 4; ks++) {
            int ch = ((ks*2 + hi) ^ f7) * 8;
            bf16x8 a0 = *(const bf16x8*)&ab[(wm +      fr)*KSTEP + ch];
            bf16x8 a1 = *(const bf16x8*)&ab[(wm + 32 + fr)*KSTEP + ch];
            bf16x8 b0 = *(const bf16x8*)&bb[(wn +      fr)*KSTEP + ch];
            acc[0] = MFMA32(a0, b0, acc[0]);
            acc[1] = MFMA32(a1, b0, acc[1]);
        }
        __builtin_amdgcn_s_setprio(0);
        asm volatile("s_waitcnt lgkmcnt(0)" ::: "memory");
        __builtin_amdgcn_sched_barrier(0);
        __builtin_amdgcn_s_barrier();
        cur ^= 1;
    }

    // C/D: col = lane&31, row = (reg&3) + 8*(reg>>2) + 4*(lane>>5)  [m74/m101]
    int gcol = nt*BN + wn + fr;
    bool cok = gcol < H_;
    float bias = cok ? b1e[gcol] : 0.f;
    #pragma unroll
    for (int mf = 0; mf < 2; mf++) {
        #pragma unroll
        for (int r = 0; r < 16; r++) {
            int row = wm + mf*32 + (r & 3) + 8*(r >> 2) + 4*hi;
            if (row < valid) {
                float v = 0.f;
                if (cok) v = fast_gelu(acc[mf][r] + bias);
                heb[(size_t)(offset + m0 + row)*HP + gcol] = f2bf(v);
            }
        }
    }
}

// out += w * (He @ W2e^T + b2e).  MODE 0: plain store (shared, w=1); MODE 1: atomicAdd
template<int MODE>
__device__ __forceinline__ void gemm2_body(u16* As, u16* Bs,
    const u16* heb, const u16* w2e, const float* b2e, const float* sw,
    int offset, int m0, int valid, int nt, float* out, const int* stok)
{
    int t = threadIdx.x, wid = t >> 6, lane = t & 63;
    int rl = lane >> 3, cl = lane & 7;
    int sg = cl ^ rl;

    const u16* aP[2]; const u16* bP[2]; int dOff[2];
    #pragma unroll
    for (int c = 0; c < 2; c++) {
        int row = wid*16 + c*8 + rl;
        int ar = min(row, valid-1);
        aP[c] = heb + (size_t)(offset + m0 + ar)*HP + sg*8;
        int jg = nt*BN + row;             // < 1024 always
        bP[c] = w2e + (size_t)jg*HP + sg*8;
        dOff[c] = (wid*16 + c*8)*KSTEP;
    }

    int wm = (wid >> 2)*64, wn = (wid & 3)*32;
    int fr = lane & 31, hi = lane >> 5, f7 = lane & 7;
    f32x16 acc[2] = {};

    #pragma unroll
    for (int c = 0; c < 2; c++) {
        gload_lds16(aP[c], As + dOff[c]);
        gload_lds16(bP[c], Bs + dOff[c]);
    }
    constexpr int nIter = HP/KSTEP;      // 22
    int cur = 0;
    for (int tt = 0; tt < nIter; ++tt) {
        if (tt + 1 < nIter) {
            int bo2 = (cur^1)*ATILE;
            int ko = (tt+1)*KSTEP;
            #pragma unroll
            for (int c = 0; c < 2; c++) {
                gload_lds16(aP[c]+ko, As + bo2 + dOff[c]);
                gload_lds16(bP[c]+ko, Bs + bo2 + dOff[c]);
            }
            asm volatile("s_waitcnt vmcnt(4)" ::: "memory");
        } else {
            asm volatile("s_waitcnt vmcnt(0)" ::: "memory");
        }
        __builtin_amdgcn_s_barrier();
        __builtin_amdgcn_sched_barrier(0);
        const u16* ab = As + cur*ATILE;
        const u16* bb = Bs + cur*ATILE;
        __builtin_amdgcn_s_setprio(1);
        #pragma unroll
        for (int ks = 0; ks < 4; ks++) {
            int ch = ((ks*2 + hi) ^ f7) * 8;
            bf16x8 a0 = *(const bf16x8*)&ab[(wm +      fr)*KSTEP + ch];
            bf16x8 a1 = *(const bf16x8*)&ab[(wm + 32 + fr)*KSTEP + ch];
            bf16x8 b0 = *(const bf16x8*)&bb[(wn +      fr)*KSTEP + ch];
            acc[0] = MFMA32(a0, b0, acc[0]);
            acc[1] = MFMA32(a1, b0, acc[1]);
        }
        __builtin_amdgcn_s_setprio(0);
        asm volatile("s_waitcnt lgkmcnt(0)" ::: "memory");
        __builtin_amdgcn_sched_barrier(0);
        __builtin_amdgcn_s_barrier();
        cur ^= 1;
    }

    int gcol = nt*BN + wn + fr;
    float bias = b2e[gcol];
    #pragma unroll
    for (int mf = 0; mf < 2; mf++) {
        #pragma unroll
        for (int r = 0; r < 16; r++) {
            int row = wm + mf*32 + (r & 3) + 8*(r >> 2) + 4*hi;
            if (row < valid) {
                if (MODE == 0) {
                    out[(size_t)(m0 + row)*D_ + gcol] = acc[mf][r] + bias;
                } else {
                    int slot = offset + m0 + row;
                    atomicAdd(out + (size_t)stok[slot]*D_ + gcol,
                              sw[slot]*(acc[mf][r] + bias));
                }
            }
        }
    }
}

// ================= finalize (512 threads): counts, offsets, losses, scatter =================
__device__ void finalize_body(char* smem,
    const int* tidx, const float* tw, const float* probs, const float* lse2,
    int* ci, int* stok, float* sw, float* out)
{
    int*   lt   = (int*)smem;               // 4096 ints (16 KiB)
    float* psum = (float*)(smem + 16384);
    float* lsum = (float*)(smem + 16384 + 32);
    int*   cntS = (int*)(smem + 16448);
    int*   offS = (int*)(smem + 16480);
    int t = threadIdx.x;
    if (t < 8) { psum[t] = 0.f; cntS[t] = 0; }
    if (t == 0) *lsum = 0.f;
    for (int i = t; i < NTOK*2; i += 512) lt[i] = tidx[i];
    __syncthreads();
    float lp[E_] = {}; float ll = 0.f;
    for (int n = t; n < NTOK; n += 512) {
        #pragma unroll
        for (int e = 0; e < E_; e++) lp[e] += probs[n*8+e];
        ll += lse2[n];
    }
    #pragma unroll
    for (int e = 0; e < E_; e++) atomicAdd(&psum[e], lp[e]);
    atomicAdd(lsum, ll);
    int wid = t >> 6, lane = t & 63;
    if (wid < 7) {
        int c = 0;
        for (int i = lane; i < NTOK*2; i += 64) c += (lt[i] == wid) ? 1 : 0;
        #pragma unroll
        for (int m = 32; m >= 1; m >>= 1) c += __shfl_xor(c, m);
        if (lane == 0) cntS[wid] = c;
    } else {
        for (int n = lane; n < NTOK; n += 64) {
            stok[SHARED_BASE+n] = n; sw[SHARED_BASE+n] = 1.f;
        }
    }
    __syncthreads();
    if (t == 0) {
        int o = 0;
        for (int e = 0; e < E_; e++) { offS[e] = o; o += cntS[e]; }
        offS[7] = SHARED_BASE; cntS[7] = NTOK;
        float la = 0.f;
        for (int e = 0; e < E_; e++)
            la += ((float)cntS[e] / (float)(NTOK*2)) * (psum[e] / (float)NTOK);
        out[(size_t)NTOK*D_]     = 0.01f * 7.f * la;
        out[(size_t)NTOK*D_ + 1] = 0.001f * (*lsum) / (float)NTOK;
        #pragma unroll
        for (int e = 0; e < 8; e++) { ci[CI_COUNT+e] = cntS[e]; ci[CI_OFF+e] = offS[e]; }
    }
    __syncthreads();
    if (wid < 7) {
        int base = offS[wid], run = 0;
        for (int c0 = 0; c0 < NTOK*2; c0 += 64) {
            bool m = (lt[c0 + lane] == wid);
            unsigned long long bal = __ballot(m);
            int pre = __popcll(bal & ((1ull << lane) - 1ull));
            if (m) {
                int i = c0 + lane;
                int s = base + run + pre;
                stok[s] = i >> 1; sw[s] = tw[i];
            }
            run += __popcll(bal);
        }
    }
}

// ==== k1: router (0..511) || ALL weight converts (512..1535) — NO LDS, full occupancy ====
__global__ void prep_kernel(
    const float* __restrict__ x, const float* __restrict__ Wg,
    const float* __restrict__ W1, const float* __restrict__ Ws1,
    const float* __restrict__ W2, const float* __restrict__ Ws2,
    const float* __restrict__ b1, const float* __restrict__ bs1,
    const float* __restrict__ b2, const float* __restrict__ bs2,
    int* __restrict__ tidx, float* __restrict__ tw,
    float* __restrict__ probs, float* __restrict__ lse2,
    u16* __restrict__ xb, u16* __restrict__ w1b, u16* __restrict__ w2b,
    float* __restrict__ b1all, float* __restrict__ b2all)
{
    int b = blockIdx.x;
    if (b < 512) {
        int wid = threadIdx.x >> 6, lane = threadIdx.x & 63;
        int n = b*4 + wid;
        float p[E_] = {};
        const float* xr = x + (size_t)n*D_;
        u16* xbr = xb + (size_t)n*D_;
        #pragma unroll
        for (int j = 0; j < 4; j++) {
            int d0 = lane*4 + j*256;
            float4 xv = *(const float4*)(xr + d0);
            ushort4 h;
            h.x = f2bf(xv.x); h.y = f2bf(xv.y); h.z = f2bf(xv.z); h.w = f2bf(xv.w);
            *(ushort4*)(xbr + d0) = h;
            #pragma unroll
            for (int e = 0; e < E_; e++) {
                float4 wv = *(const float4*)(Wg + e*D_ + d0);
                p[e] += xv.x*wv.x + xv.y*wv.y + xv.z*wv.z + xv.w*wv.w;
            }
        }
        #pragma unroll
        for (int e = 0; e < E_; e++) {
            float v = p[e];
            #pragma unroll
            for (int m = 32; m >= 1; m >>= 1) v += __shfl_xor(v, m);
            p[e] = v;
        }
        if (lane == 0) {
            float mx = p[0];
            #pragma unroll
            for (int e = 1; e < E_; e++) mx = fmaxf(mx, p[e]);
            float pr[E_], sum = 0.f;
            #pragma unroll
            for (int e = 0; e < E_; e++) { pr[e] = __expf(p[e]-mx); sum += pr[e]; }
            float lse = mx + logf(sum);
            int i0 = 0;
            #pragma unroll
            for (int e = 1; e < E_; e++) if (p[e] > p[i0]) i0 = e;
            int i1 = -1;
            #pragma unroll
            for (int e = 0; e < E_; e++) if (e != i0 && (i1 < 0 || p[e] > p[i1])) i1 = e;
            float g = expf(p[i1] - p[i0]);
            tidx[n*2] = i0; tidx[n*2+1] = i1;
            tw[n*2] = 1.f/(1.f+g); tw[n*2+1] = g/(1.f+g);
            float inv = 1.f/sum;
            #pragma unroll
            for (int e = 0; e < E_; e++) probs[n*8+e] = pr[e]*inv;
            lse2[n] = lse*lse;
        }
        return;
    }
    // ---- converts: W1 | W2 | b1 | b2 ----
    const size_t G1 = (size_t)NE*H_*D_/8;
    const size_t G2 = (size_t)NE*D_*HP/8;
    const size_t W1FLAT = (size_t)7*H_*D_;
    const size_t total = G1 + G2 + (size_t)NE*H_ + (size_t)NE*D_;
    const size_t stride = (size_t)1024*256;
    for (size_t i = (size_t)(b-512)*256 + threadIdx.x; i < total; i += stride) {
        size_t k = i;
        if (k < G1) {
            size_t base = k*8;
            const float* src = (base < W1FLAT) ? (W1 + base) : (Ws1 + (base - W1FLAT));
            const float4* s = (const float4*)src;
            ((uint4*)w1b)[k] = pack8(s[0], s[1]);
            continue;
        }
        k -= G1;
        if (k < G2) {
            size_t base = k*8;
            size_t e = base/((size_t)D_*HP);
            size_t rr = base - e*(size_t)D_*HP;
            size_t drow = rr/HP, h0 = rr - drow*HP;
            const float* srow = (e < 7) ? (W2 + ((size_t)e*D_ + drow)*H_)
                                        : (Ws2 + drow*(size_t)H_);
            union { u16 h[8]; uint4 v; } u;
            #pragma unroll
            for (int q = 0; q < 8; q++) {
                size_t h = h0 + q;
                u.h[q] = (h < (size_t)H_) ? f2bf(srow[h]) : (u16)0;
            }
            ((uint4*)w2b)[k] = u.v;
            continue;
        }
        k -= G2;
        if (k < (size_t)NE*H_) {
            size_t e = k/H_, j = k - e*H_;
            b1all[k] = (e < 7) ? b1[k] : bs1[j];
        } else {
            size_t kk = k - (size_t)NE*H_;
            size_t e = kk/D_, j = kk - e*D_;
            b2all[kk] = (e < 7) ? b2[kk] : bs2[j];
        }
    }
}

// ===== k2: finalize (block 0) || shared-expert GEMM1 (1..176) =====
__global__ __launch_bounds__(512, 4) void k2_kernel(
    const int* __restrict__ tidx, const float* __restrict__ tw,
    const float* __restrict__ probs, const float* __restrict__ lse2,
    int* __restrict__ ci, int* __restrict__ stok, float* __restrict__ sw,
    float* __restrict__ out,
    const u16* __restrict__ xb, const u16* __restrict__ w1b,
    const float* __restrict__ b1all, u16* __restrict__ heb)
{
    __shared__ u16 As[2*ATILE];
    __shared__ u16 Bs[2*ATILE];
    int b = blockIdx.x;
    if (b == 0) {
        finalize_body((char*)As, tidx, tw, probs, lse2, ci, stok, sw, out);
        return;
    }
    int tdx = b - 1;
    int mt = tdx/11, nt = tdx - mt*11;
    gemm1_body<false>(As, Bs, xb, w1b + (size_t)7*H_*D_, b1all + 7*H_,
                      nullptr, SHARED_BASE, mt*BM, BM, nt, heb);
}

// ===== k3: routed GEMM1 (XCD-pinned, yb<176) || shared GEMM2 (yb>=176) =====
__global__ __launch_bounds__(512, 4) void k3_kernel(
    const int* __restrict__ ci, const int* __restrict__ stok,
    const u16* __restrict__ xb, const u16* __restrict__ w1b,
    const float* __restrict__ b1all, u16* __restrict__ heb,
    const u16* __restrict__ w2b, const float* __restrict__ b2all,
    float* __restrict__ out)
{
    __shared__ u16 As[2*ATILE];
    __shared__ u16 Bs[2*ATILE];
    int x = blockIdx.x, yb = blockIdx.y;
    if (yb < 176) {
        if (x == 7) return;
        int e = x, mt = yb/11, nt = yb - mt*11;
        int count = ci[CI_COUNT+e];
        int m0 = mt*BM;
        if (m0 >= count) return;
        gemm1_body<true>(As, Bs, xb, w1b + (size_t)e*H_*D_, b1all + e*H_,
                         stok, ci[CI_OFF+e], m0, min(BM, count-m0), nt, heb);
    } else {
        int idx = (yb - 176)*8 + x;       // 0..127
        int mt = idx >> 3, nt = idx & 7;
        gemm2_body<0>(As, Bs, heb, w2b + (size_t)7*D_*HP, b2all + 7*D_,
                      nullptr, SHARED_BASE, mt*BM, BM, nt, out, nullptr);
    }
}

// ===== k4: routed GEMM2 (XCD-pinned), atomicAdd into out =====
__global__ __launch_bounds__(512, 4) void k4_kernel(
    const int* __restrict__ ci, const int* __restrict__ stok, const float* __restrict__ sw,
    const u16* __restrict__ heb, const u16* __restrict__ w2b,
    const float* __restrict__ b2all, float* __restrict__ out)
{
    __shared__ u16 As[2*ATILE];
    __shared__ u16 Bs[2*ATILE];
    int x = blockIdx.x;
    if (x == 7) return;
    int yb = blockIdx.y;
    int e = x, mt = yb >> 3, nt = yb & 7;
    int count = ci[CI_COUNT+e];
    int m0 = mt*BM;
    if (m0 >= count) return;
    gemm2_body<1>(As, Bs, heb, w2b + (size_t)e*D_*HP, b2all + e*D_,
                  sw, ci[CI_OFF+e], m0, min(BM, count-m0), nt, out, stok);
}

extern "C" void kernel_launch(void* const* d_in, const int* in_sizes, int n_in,
                              void* d_out, int out_size, void* d_ws, size_t ws_size,
                              hipStream_t stream)
{
    const float* x   = (const float*)d_in[0];
    const float* Wg  = (const float*)d_in[1];
    const float* W1  = (const float*)d_in[2];
    const float* b1  = (const float*)d_in[3];
    const float* W2  = (const float*)d_in[4];
    const float* b2  = (const float*)d_in[5];
    const float* Ws1 = (const float*)d_in[6];
    const float* bs1 = (const float*)d_in[7];
    const float* Ws2 = (const float*)d_in[8];
    const float* bs2 = (const float*)d_in[9];
    float* out = (float*)d_out;
    char* ws = (char*)d_ws;

    int*   ci    = (int*)(ws + WS_CTRL);
    int*   tidx  = (int*)(ws + WS_TIDX);
    float* tw    = (float*)(ws + WS_TW);
    float* probs = (float*)(ws + WS_PROB);
    float* lse2  = (float*)(ws + WS_LSE2);
    int*   stok  = (int*)(ws + WS_STOK);
    float* sw    = (float*)(ws + WS_SW);
    float* b1all = (float*)(ws + WS_B1);
    float* b2all = (float*)(ws + WS_B2);
    u16*   xb    = (u16*)(ws + WS_XB);
    u16*   w1b   = (u16*)(ws + WS_W1B);
    u16*   w2b   = (u16*)(ws + WS_W2B);
    u16*   heb   = (u16*)(ws + WS_HEB);

    // k1: router (512) || W1+W2+bias converts (1024) — zero LDS, full occupancy
    prep_kernel<<<1536, 256, 0, stream>>>(x, Wg, W1, Ws1, W2, Ws2, b1, bs1, b2, bs2,
                                          tidx, tw, probs, lse2, xb, w1b, w2b, b1all, b2all);
    // k2: finalize || shared-expert GEMM1 (16mt x 11nt)
    k2_kernel<<<177, 512, 0, stream>>>(tidx, tw, probs, lse2, ci, stok, sw, out,
                                       xb, w1b, b1all, heb);
    // k3: routed GEMM1 (expert->XCD pinned) || shared GEMM2
    k3_kernel<<<dim3(8, 176 + 16), 512, 0, stream>>>(ci, stok, xb, w1b, b1all, heb,
                                                     w2b, b2all, out);
    // k4: routed GEMM2, weighted atomic accumulate
    k4_kernel<<<dim3(8, 128), 512, 0, stream>>>(ci, stok, sw, heb, w2b, b2all, out);
}

// Round 9
// 140.335 us; speedup vs baseline: 1.3686x; 1.1617x over previous
//
#include <hip/hip_runtime.h>
#include <hip/hip_bf16.h>
#include <math.h>

typedef unsigned short u16;
typedef __attribute__((ext_vector_type(8))) short bf16x8;
typedef __attribute__((ext_vector_type(16))) float f32x16;

constexpr int D_ = 1024;
constexpr int H_ = 1365;
constexpr int E_ = 7;
constexpr int NTOK = 2048;
constexpr int HP = 1408;          // H padded to multiple of 64
constexpr int NE = 8;             // 7 routed + 1 shared
constexpr int SHARED_BASE = 4096;
constexpr int SLOTS = 6144;

#define CI_COUNT 0
#define CI_OFF   8

constexpr size_t WS_CTRL = 0;
constexpr size_t WS_TIDX = 256;
constexpr size_t WS_TW   = WS_TIDX + (size_t)NTOK*2*4;
constexpr size_t WS_PROB = WS_TW   + (size_t)NTOK*2*4;
constexpr size_t WS_LSE2 = WS_PROB + (size_t)NTOK*8*4;
constexpr size_t WS_STOK = WS_LSE2 + (size_t)NTOK*4;
constexpr size_t WS_SW   = WS_STOK + (size_t)SLOTS*4;
constexpr size_t WS_B1   = WS_SW   + (size_t)SLOTS*4;
constexpr size_t WS_B2   = WS_B1   + (size_t)NE*H_*4;
constexpr size_t WS_XB   = ((WS_B2 + (size_t)NE*D_*4) + 255) & ~(size_t)255;
constexpr size_t WS_W1B  = WS_XB  + (size_t)NTOK*D_*2;
constexpr size_t WS_W2B  = WS_W1B + (size_t)NE*H_*D_*2;
constexpr size_t WS_HEB  = WS_W2B + (size_t)NE*D_*HP*2;

__device__ __forceinline__ u16 f2bf(float f) {
    __hip_bfloat16 h = __float2bfloat16(f);
    return __builtin_bit_cast(u16, h);
}

__device__ __forceinline__ void gload_lds16(const u16* g, u16* l) {
    __builtin_amdgcn_global_load_lds(
        (const __attribute__((address_space(1))) void*)g,
        (__attribute__((address_space(3))) void*)l, 16, 0, 0);
}

__device__ __forceinline__ uint4 pack8(float4 a, float4 b) {
    union { u16 h[8]; uint4 v; } u;
    u.h[0]=f2bf(a.x); u.h[1]=f2bf(a.y); u.h[2]=f2bf(a.z); u.h[3]=f2bf(a.w);
    u.h[4]=f2bf(b.x); u.h[5]=f2bf(b.y); u.h[6]=f2bf(b.z); u.h[7]=f2bf(b.w);
    return u.v;
}

// tanh-form GELU (|err| ~3e-3, below bf16 quantization of He)
__device__ __forceinline__ float fast_gelu(float v) {
    float u = 0.7978845608f * v * (1.f + 0.044715f * v * v);
    float e = __expf(2.f * u);
    float t = 1.f - 2.f / (e + 1.f);
    return 0.5f * v * (1.f + t);
}

// ===== GEMM core: 128x128 block, BK=64, 512 thr / 8 waves of 64x32, mfma 32x32x16 =====
#define BM 128
#define BN 128
#define KSTEP 64
#define ATILE (BM*KSTEP)    // 8192 elems = 16 KiB
// LDS: 2 buffers * (16+16) KiB = 64 KiB -> 2 blocks/CU, 16 waves/CU (4/SIMD)

#define MFMA32(a,b,c) __builtin_amdgcn_mfma_f32_32x32x16_bf16(a, b, c, 0, 0, 0)

template<bool USE_STOK>
__device__ __forceinline__ void gemm1_body(u16* As, u16* Bs,
    const u16* xb, const u16* w1e, const float* b1e,
    const int* stok, int offset, int m0, int valid, int nt,
    u16* heb)
{
    int t = threadIdx.x, wid = t >> 6, lane = t & 63;
    int rl = lane >> 3, cl = lane & 7;
    int sg = cl ^ rl;                    // pre-swizzled 16B-chunk (involution on row&7)

    const u16* aP[2]; const u16* bP[2]; int dOff[2];
    #pragma unroll
    for (int c = 0; c < 2; c++) {
        int row = wid*16 + c*8 + rl;
        int ar = min(row, valid-1);
        int tok = USE_STOK ? stok[offset + m0 + ar] : (m0 + ar);
        aP[c] = xb + (size_t)tok*D_ + sg*8;
        int jg = min(nt*BN + row, H_-1);
        bP[c] = w1e + (size_t)jg*D_ + sg*8;
        dOff[c] = (wid*16 + c*8)*KSTEP;
    }

    int wm = (wid >> 2)*64, wn = (wid & 3)*32;
    int fr = lane & 31, hi = lane >> 5, f7 = lane & 7;
    f32x16 acc[2] = {};

    #pragma unroll
    for (int c = 0; c < 2; c++) {        // prologue: stage tile 0 into buf 0
        gload_lds16(aP[c], As + dOff[c]);
        gload_lds16(bP[c], Bs + dOff[c]);
    }
    constexpr int nIter = D_/KSTEP;      // 16
    int cur = 0;
    for (int tt = 0; tt < nIter; ++tt) {
        if (tt + 1 < nIter) {
            int bo2 = (cur^1)*ATILE;
            int ko = (tt+1)*KSTEP;
            #pragma unroll
            for (int c = 0; c < 2; c++) {
                gload_lds16(aP[c]+ko, As + bo2 + dOff[c]);
                gload_lds16(bP[c]+ko, Bs + bo2 + dOff[c]);
            }
            asm volatile("s_waitcnt vmcnt(4)" ::: "memory");
        } else {
            asm volatile("s_waitcnt vmcnt(0)" ::: "memory");
        }
        __builtin_amdgcn_s_barrier();
        __builtin_amdgcn_sched_barrier(0);
        const u16* ab = As + cur*ATILE;
        const u16* bb = Bs + cur*ATILE;
        __builtin_amdgcn_s_setprio(1);
        #pragma unroll
        for (int ks = 0; ks < 4; ks++) {
            int ch = ((ks*2 + hi) ^ f7) * 8;
            bf16x8 a0 = *(const bf16x8*)&ab[(wm +      fr)*KSTEP + ch];
            bf16x8 a1 = *(const bf16x8*)&ab[(wm + 32 + fr)*KSTEP + ch];
            bf16x8 b0 = *(const bf16x8*)&bb[(wn +      fr)*KSTEP + ch];
            acc[0] = MFMA32(a0, b0, acc[0]);
            acc[1] = MFMA32(a1, b0, acc[1]);
        }
        __builtin_amdgcn_s_setprio(0);
        asm volatile("s_waitcnt lgkmcnt(0)" ::: "memory");
        __builtin_amdgcn_sched_barrier(0);
        __builtin_amdgcn_s_barrier();
        cur ^= 1;
    }

    // C/D: col = lane&31, row = (reg&3) + 8*(reg>>2) + 4*(lane>>5)  [m74/m101]
    int gcol = nt*BN + wn + fr;
    bool cok = gcol < H_;
    float bias = cok ? b1e[gcol] : 0.f;
    #pragma unroll
    for (int mf = 0; mf < 2; mf++) {
        #pragma unroll
        for (int r = 0; r < 16; r++) {
            int row = wm + mf*32 + (r & 3) + 8*(r >> 2) + 4*hi;
            if (row < valid) {
                float v = 0.f;
                if (cok) v = fast_gelu(acc[mf][r] + bias);
                heb[(size_t)(offset + m0 + row)*HP + gcol] = f2bf(v);
            }
        }
    }
}

// out += w * (He @ W2e^T + b2e).  MODE 0: plain store (shared, w=1); MODE 1: atomicAdd
template<int MODE>
__device__ __forceinline__ void gemm2_body(u16* As, u16* Bs,
    const u16* heb, const u16* w2e, const float* b2e, const float* sw,
    int offset, int m0, int valid, int nt, float* out, const int* stok)
{
    int t = threadIdx.x, wid = t >> 6, lane = t & 63;
    int rl = lane >> 3, cl = lane & 7;
    int sg = cl ^ rl;

    const u16* aP[2]; const u16* bP[2]; int dOff[2];
    #pragma unroll
    for (int c = 0; c < 2; c++) {
        int row = wid*16 + c*8 + rl;
        int ar = min(row, valid-1);
        aP[c] = heb + (size_t)(offset + m0 + ar)*HP + sg*8;
        int jg = nt*BN + row;             // < 1024 always
        bP[c] = w2e + (size_t)jg*HP + sg*8;
        dOff[c] = (wid*16 + c*8)*KSTEP;
    }

    int wm = (wid >> 2)*64, wn = (wid & 3)*32;
    int fr = lane & 31, hi = lane >> 5, f7 = lane & 7;
    f32x16 acc[2] = {};

    #pragma unroll
    for (int c = 0; c < 2; c++) {
        gload_lds16(aP[c], As + dOff[c]);
        gload_lds16(bP[c], Bs + dOff[c]);
    }
    constexpr int nIter = HP/KSTEP;      // 22
    int cur = 0;
    for (int tt = 0; tt < nIter; ++tt) {
        if (tt + 1 < nIter) {
            int bo2 = (cur^1)*ATILE;
            int ko = (tt+1)*KSTEP;
            #pragma unroll
            for (int c = 0; c < 2; c++) {
                gload_lds16(aP[c]+ko, As + bo2 + dOff[c]);
                gload_lds16(bP[c]+ko, Bs + bo2 + dOff[c]);
            }
            asm volatile("s_waitcnt vmcnt(4)" ::: "memory");
        } else {
            asm volatile("s_waitcnt vmcnt(0)" ::: "memory");
        }
        __builtin_amdgcn_s_barrier();
        __builtin_amdgcn_sched_barrier(0);
        const u16* ab = As + cur*ATILE;
        const u16* bb = Bs + cur*ATILE;
        __builtin_amdgcn_s_setprio(1);
        #pragma unroll
        for (int ks = 0; ks < 4; ks++) {
            int ch = ((ks*2 + hi) ^ f7) * 8;
            bf16x8 a0 = *(const bf16x8*)&ab[(wm +      fr)*KSTEP + ch];
            bf16x8 a1 = *(const bf16x8*)&ab[(wm + 32 + fr)*KSTEP + ch];
            bf16x8 b0 = *(const bf16x8*)&bb[(wn +      fr)*KSTEP + ch];
            acc[0] = MFMA32(a0, b0, acc[0]);
            acc[1] = MFMA32(a1, b0, acc[1]);
        }
        __builtin_amdgcn_s_setprio(0);
        asm volatile("s_waitcnt lgkmcnt(0)" ::: "memory");
        __builtin_amdgcn_sched_barrier(0);
        __builtin_amdgcn_s_barrier();
        cur ^= 1;
    }

    int gcol = nt*BN + wn + fr;
    float bias = b2e[gcol];
    #pragma unroll
    for (int mf = 0; mf < 2; mf++) {
        #pragma unroll
        for (int r = 0; r < 16; r++) {
            int row = wm + mf*32 + (r & 3) + 8*(r >> 2) + 4*hi;
            if (row < valid) {
                if (MODE == 0) {
                    out[(size_t)(m0 + row)*D_ + gcol] = acc[mf][r] + bias;
                } else {
                    int slot = offset + m0 + row;
                    atomicAdd(out + (size_t)stok[slot]*D_ + gcol,
                              sw[slot]*(acc[mf][r] + bias));
                }
            }
        }
    }
}

// ================= finalize (512 threads): counts, offsets, losses, scatter =================
__device__ void finalize_body(char* smem,
    const int* tidx, const float* tw, const float* probs, const float* lse2,
    int* ci, int* stok, float* sw, float* out)
{
    int*   lt   = (int*)smem;               // 4096 ints (16 KiB)
    float* psum = (float*)(smem + 16384);
    float* lsum = (float*)(smem + 16384 + 32);
    int*   cntS = (int*)(smem + 16448);
    int*   offS = (int*)(smem + 16480);
    int t = threadIdx.x;
    if (t < 8) { psum[t] = 0.f; cntS[t] = 0; }
    if (t == 0) *lsum = 0.f;
    for (int i = t; i < NTOK*2; i += 512) lt[i] = tidx[i];
    __syncthreads();
    float lp[E_] = {}; float ll = 0.f;
    for (int n = t; n < NTOK; n += 512) {
        #pragma unroll
        for (int e = 0; e < E_; e++) lp[e] += probs[n*8+e];
        ll += lse2[n];
    }
    #pragma unroll
    for (int e = 0; e < E_; e++) atomicAdd(&psum[e], lp[e]);
    atomicAdd(lsum, ll);
    int wid = t >> 6, lane = t & 63;
    if (wid < 7) {
        int c = 0;
        for (int i = lane; i < NTOK*2; i += 64) c += (lt[i] == wid) ? 1 : 0;
        #pragma unroll
        for (int m = 32; m >= 1; m >>= 1) c += __shfl_xor(c, m);
        if (lane == 0) cntS[wid] = c;
    } else {
        for (int n = lane; n < NTOK; n += 64) {
            stok[SHARED_BASE+n] = n; sw[SHARED_BASE+n] = 1.f;
        }
    }
    __syncthreads();
    if (t == 0) {
        int o = 0;
        for (int e = 0; e < E_; e++) { offS[e] = o; o += cntS[e]; }
        offS[7] = SHARED_BASE; cntS[7] = NTOK;
        float la = 0.f;
        for (int e = 0; e < E_; e++)
            la += ((float)cntS[e] / (float)(NTOK*2)) * (psum[e] / (float)NTOK);
        out[(size_t)NTOK*D_]     = 0.01f * 7.f * la;
        out[(size_t)NTOK*D_ + 1] = 0.001f * (*lsum) / (float)NTOK;
        #pragma unroll
        for (int e = 0; e < 8; e++) { ci[CI_COUNT+e] = cntS[e]; ci[CI_OFF+e] = offS[e]; }
    }
    __syncthreads();
    if (wid < 7) {
        int base = offS[wid], run = 0;
        for (int c0 = 0; c0 < NTOK*2; c0 += 64) {
            bool m = (lt[c0 + lane] == wid);
            unsigned long long bal = __ballot(m);
            int pre = __popcll(bal & ((1ull << lane) - 1ull));
            if (m) {
                int i = c0 + lane;
                int s = base + run + pre;
                stok[s] = i >> 1; sw[s] = tw[i];
            }
            run += __popcll(bal);
        }
    }
}

// ==== k1: router (0..511) || W1 + b1 convert (512..1535) — NO LDS, full occupancy ====
__global__ void prep_kernel(
    const float* __restrict__ x, const float* __restrict__ Wg,
    const float* __restrict__ W1, const float* __restrict__ Ws1,
    const float* __restrict__ b1, const float* __restrict__ bs1,
    int* __restrict__ tidx, float* __restrict__ tw,
    float* __restrict__ probs, float* __restrict__ lse2,
    u16* __restrict__ xb, u16* __restrict__ w1b, float* __restrict__ b1all)
{
    int b = blockIdx.x;
    if (b < 512) {
        int wid = threadIdx.x >> 6, lane = threadIdx.x & 63;
        int n = b*4 + wid;
        float p[E_] = {};
        const float* xr = x + (size_t)n*D_;
        u16* xbr = xb + (size_t)n*D_;
        #pragma unroll
        for (int j = 0; j < 4; j++) {
            int d0 = lane*4 + j*256;
            float4 xv = *(const float4*)(xr + d0);
            ushort4 h;
            h.x = f2bf(xv.x); h.y = f2bf(xv.y); h.z = f2bf(xv.z); h.w = f2bf(xv.w);
            *(ushort4*)(xbr + d0) = h;
            #pragma unroll
            for (int e = 0; e < E_; e++) {
                float4 wv = *(const float4*)(Wg + e*D_ + d0);
                p[e] += xv.x*wv.x + xv.y*wv.y + xv.z*wv.z + xv.w*wv.w;
            }
        }
        #pragma unroll
        for (int e = 0; e < E_; e++) {
            float v = p[e];
            #pragma unroll
            for (int m = 32; m >= 1; m >>= 1) v += __shfl_xor(v, m);
            p[e] = v;
        }
        if (lane == 0) {
            float mx = p[0];
            #pragma unroll
            for (int e = 1; e < E_; e++) mx = fmaxf(mx, p[e]);
            float pr[E_], sum = 0.f;
            #pragma unroll
            for (int e = 0; e < E_; e++) { pr[e] = __expf(p[e]-mx); sum += pr[e]; }
            float lse = mx + logf(sum);
            int i0 = 0;
            #pragma unroll
            for (int e = 1; e < E_; e++) if (p[e] > p[i0]) i0 = e;
            int i1 = -1;
            #pragma unroll
            for (int e = 0; e < E_; e++) if (e != i0 && (i1 < 0 || p[e] > p[i1])) i1 = e;
            float g = expf(p[i1] - p[i0]);
            tidx[n*2] = i0; tidx[n*2+1] = i1;
            tw[n*2] = 1.f/(1.f+g); tw[n*2+1] = g/(1.f+g);
            float inv = 1.f/sum;
            #pragma unroll
            for (int e = 0; e < E_; e++) probs[n*8+e] = pr[e]*inv;
            lse2[n] = lse*lse;
        }
        return;
    }
    // ---- W1 (flat vectorized) + b1 biases, all 32-bit indexing ----
    const unsigned G1 = (unsigned)(NE*H_*D_/8);      // 1,397,760 uint4 groups
    const unsigned W1FLAT = 7u*(unsigned)(H_*D_);
    const unsigned total = G1 + (unsigned)(NE*H_);
    const unsigned stride = 1024u*256u;
    for (unsigned i = (unsigned)(b-512)*256u + threadIdx.x; i < total; i += stride) {
        if (i < G1) {
            unsigned base = i*8u;
            const float* src = (base < W1FLAT) ? (W1 + base) : (Ws1 + (base - W1FLAT));
            const float4* s = (const float4*)src;
            ((uint4*)w1b)[i] = pack8(s[0], s[1]);
        } else {
            unsigned k = i - G1;
            unsigned e = k / 1365u, j = k - e*1365u;
            b1all[k] = (e < 7u) ? b1[k] : bs1[j];
        }
    }
}

// ===== k2: finalize (blk 0) || shared GEMM1 (1..176) || W2+b2 convert (177..1008) =====
__global__ __launch_bounds__(512, 4) void k2_kernel(
    const float* __restrict__ W2, const float* __restrict__ Ws2,
    const float* __restrict__ b2, const float* __restrict__ bs2,
    u16* __restrict__ w2b, float* __restrict__ b2all,
    const int* __restrict__ tidx, const float* __restrict__ tw,
    const float* __restrict__ probs, const float* __restrict__ lse2,
    int* __restrict__ ci, int* __restrict__ stok, float* __restrict__ sw,
    float* __restrict__ out,
    const u16* __restrict__ xb, const u16* __restrict__ w1b,
    const float* __restrict__ b1all, u16* __restrict__ heb)
{
    __shared__ u16 As[2*ATILE];
    __shared__ u16 Bs[2*ATILE];
    int b = blockIdx.x;
    if (b == 0) {
        finalize_body((char*)As, tidx, tw, probs, lse2, ci, stok, sw, out);
        return;
    }
    if (b <= 176) {
        int tdx = b - 1;
        int mt = tdx/11, nt = tdx - mt*11;
        gemm1_body<false>(As, Bs, xb, w1b + (size_t)7*H_*D_, b1all + 7*H_,
                          nullptr, SHARED_BASE, mt*BM, BM, nt, heb);
        return;
    }
    // ---- W2 convert: source-driven float4 groups + b2 biases + w2b pad-zero ----
    const unsigned DH  = (unsigned)(D_*H_);          // 1,397,760
    const unsigned G2v = 2u*DH;                      // 8*DH/4 float4 groups
    const unsigned BIAS = (unsigned)(NE*D_/4);       // 2048 float4 bias copies
    const unsigned PAD  = (unsigned)(NE*D_)*(unsigned)(HP-H_);  // 352,256 pad elems
    const unsigned total = G2v + BIAS + PAD;
    const unsigned stride = 832u*512u;
    for (unsigned g = (unsigned)(b-177)*512u + threadIdx.x; g < total; g += stride) {
        if (g < G2v) {
            unsigned base = g*4u;
            unsigned ec = base / DH;
            unsigned r  = base - ec*DH;
            unsigned drow = r / 1365u;
            unsigned h  = r - drow*1365u;
            const float* src = (ec < 7u) ? (W2 + base) : (Ws2 + (base - 7u*DH));
            float4 v = *(const float4*)src;
            float vv[4] = {v.x, v.y, v.z, v.w};
            u16* rb = w2b + ((size_t)ec*D_ + drow)*HP;
            if (h + 3u < 1365u) {
                #pragma unroll
                for (int q = 0; q < 4; q++) rb[h+q] = f2bf(vv[q]);
            } else {
                #pragma unroll
                for (int q = 0; q < 4; q++) {
                    unsigned hq = h + q, dr = 0;
                    if (hq >= 1365u) { hq -= 1365u; dr = 1; }
                    rb[(size_t)dr*HP + hq] = f2bf(vv[q]);
                }
            }
            continue;
        }
        unsigned k = g - G2v;
        if (k < BIAS) {
            unsigned base = k*4u;
            unsigned e = base >> 10, j = base & 1023u;
            float4 v = (e < 7u) ? *(const float4*)(b2 + base) : *(const float4*)(bs2 + j);
            *(float4*)(b2all + base) = v;
            continue;
        }
        k -= BIAS;                           // pad elem: row = k/43, j = k%43
        unsigned row = k / 43u, j = k - row*43u;
        w2b[(size_t)row*HP + 1365u + j] = 0;
    }
}

// ===== k3: routed GEMM1 (XCD-pinned, yb<176) || shared GEMM2 (yb>=176) =====
__global__ __launch_bounds__(512, 4) void k3_kernel(
    const int* __restrict__ ci, const int* __restrict__ stok,
    const u16* __restrict__ xb, const u16* __restrict__ w1b,
    const float* __restrict__ b1all, u16* __restrict__ heb,
    const u16* __restrict__ w2b, const float* __restrict__ b2all,
    float* __restrict__ out)
{
    __shared__ u16 As[2*ATILE];
    __shared__ u16 Bs[2*ATILE];
    int x = blockIdx.x, yb = blockIdx.y;
    if (yb < 176) {
        if (x == 7) return;
        int e = x, mt = yb/11, nt = yb - mt*11;
        int count = ci[CI_COUNT+e];
        int m0 = mt*BM;
        if (m0 >= count) return;
        gemm1_body<true>(As, Bs, xb, w1b + (size_t)e*H_*D_, b1all + e*H_,
                         stok, ci[CI_OFF+e], m0, min(BM, count-m0), nt, heb);
    } else {
        int idx = (yb - 176)*8 + x;       // 0..127
        int mt = idx >> 3, nt = idx & 7;
        gemm2_body<0>(As, Bs, heb, w2b + (size_t)7*D_*HP, b2all + 7*D_,
                      nullptr, SHARED_BASE, mt*BM, BM, nt, out, nullptr);
    }
}

// ===== k4: routed GEMM2 (XCD-pinned), atomicAdd into out =====
__global__ __launch_bounds__(512, 4) void k4_kernel(
    const int* __restrict__ ci, const int* __restrict__ stok, const float* __restrict__ sw,
    const u16* __restrict__ heb, const u16* __restrict__ w2b,
    const float* __restrict__ b2all, float* __restrict__ out)
{
    __shared__ u16 As[2*ATILE];
    __shared__ u16 Bs[2*ATILE];
    int x = blockIdx.x;
    if (x == 7) return;
    int yb = blockIdx.y;
    int e = x, mt = yb >> 3, nt = yb & 7;
    int count = ci[CI_COUNT+e];
    int m0 = mt*BM;
    if (m0 >= count) return;
    gemm2_body<1>(As, Bs, heb, w2b + (size_t)e*D_*HP, b2all + e*D_,
                  sw, ci[CI_OFF+e], m0, min(BM, count-m0), nt, out, stok);
}

extern "C" void kernel_launch(void* const* d_in, const int* in_sizes, int n_in,
                              void* d_out, int out_size, void* d_ws, size_t ws_size,
                              hipStream_t stream)
{
    const float* x   = (const float*)d_in[0];
    const float* Wg  = (const float*)d_in[1];
    const float* W1  = (const float*)d_in[2];
    const float* b1  = (const float*)d_in[3];
    const float* W2  = (const float*)d_in[4];
    const float* b2  = (const float*)d_in[5];
    const float* Ws1 = (const float*)d_in[6];
    const float* bs1 = (const float*)d_in[7];
    const float* Ws2 = (const float*)d_in[8];
    const float* bs2 = (const float*)d_in[9];
    float* out = (float*)d_out;
    char* ws = (char*)d_ws;

    int*   ci    = (int*)(ws + WS_CTRL);
    int*   tidx  = (int*)(ws + WS_TIDX);
    float* tw    = (float*)(ws + WS_TW);
    float* probs = (float*)(ws + WS_PROB);
    float* lse2  = (float*)(ws + WS_LSE2);
    int*   stok  = (int*)(ws + WS_STOK);
    float* sw    = (float*)(ws + WS_SW);
    float* b1all = (float*)(ws + WS_B1);
    float* b2all = (float*)(ws + WS_B2);
    u16*   xb    = (u16*)(ws + WS_XB);
    u16*   w1b   = (u16*)(ws + WS_W1B);
    u16*   w2b   = (u16*)(ws + WS_W2B);
    u16*   heb   = (u16*)(ws + WS_HEB);

    // k1: router (512) || W1 + b1 convert (1024) — zero LDS, full occupancy
    prep_kernel<<<1536, 256, 0, stream>>>(x, Wg, W1, Ws1, b1, bs1,
                                          tidx, tw, probs, lse2, xb, w1b, b1all);
    // k2: finalize || shared GEMM1 (176) || W2 + b2 convert (832)
    k2_kernel<<<1009, 512, 0, stream>>>(W2, Ws2, b2, bs2, w2b, b2all,
                                        tidx, tw, probs, lse2, ci, stok, sw, out,
                                        xb, w1b, b1all, heb);
    // k3: routed GEMM1 (expert->XCD pinned) || shared GEMM2
    k3_kernel<<<dim3(8, 176 + 16), 512, 0, stream>>>(ci, stok, xb, w1b, b1all, heb,
                                                     w2b, b2all, out);
    // k4: routed GEMM2, weighted atomic accumulate
    k4_kernel<<<dim3(8, 128), 512, 0, stream>>>(ci, stok, sw, heb, w2b, b2all, out);
}

// Round 10
// 134.781 us; speedup vs baseline: 1.4250x; 1.0412x over previous
//
#include <hip/hip_runtime.h>
#include <hip/hip_bf16.h>
#include <math.h>

typedef unsigned short u16;
typedef __attribute__((ext_vector_type(8))) short bf16x8;
typedef __attribute__((ext_vector_type(4))) float f32x4;

constexpr int D_ = 1024;
constexpr int H_ = 1365;
constexpr int E_ = 7;
constexpr int NTOK = 2048;
constexpr int HP = 1408;          // H padded to multiple of 64
constexpr int NE = 8;             // 7 routed + 1 shared
constexpr int SHARED_BASE = 4096;
constexpr int SLOTS = 6144;

#define CI_COUNT 0
#define CI_OFF   8

constexpr size_t WS_CTRL = 0;
constexpr size_t WS_TIDX = 256;
constexpr size_t WS_TW   = WS_TIDX + (size_t)NTOK*2*4;
constexpr size_t WS_PROB = WS_TW   + (size_t)NTOK*2*4;
constexpr size_t WS_LSE2 = WS_PROB + (size_t)NTOK*8*4;
constexpr size_t WS_STOK = WS_LSE2 + (size_t)NTOK*4;
constexpr size_t WS_SW   = WS_STOK + (size_t)SLOTS*4;
constexpr size_t WS_B1   = WS_SW   + (size_t)SLOTS*4;
constexpr size_t WS_B2   = WS_B1   + (size_t)NE*H_*4;
constexpr size_t WS_XB   = ((WS_B2 + (size_t)NE*D_*4) + 255) & ~(size_t)255;
constexpr size_t WS_W1B  = WS_XB  + (size_t)NTOK*D_*2;
constexpr size_t WS_W2B  = WS_W1B + (size_t)NE*H_*D_*2;
constexpr size_t WS_HEB  = WS_W2B + (size_t)NE*D_*HP*2;

__device__ __forceinline__ u16 f2bf(float f) {
    __hip_bfloat16 h = __float2bfloat16(f);
    return __builtin_bit_cast(u16, h);
}

__device__ __forceinline__ void gload_lds16(const u16* g, u16* l) {
    __builtin_amdgcn_global_load_lds(
        (const __attribute__((address_space(1))) void*)g,
        (__attribute__((address_space(3))) void*)l, 16, 0, 0);
}

__device__ __forceinline__ uint4 pack8(float4 a, float4 b) {
    union { u16 h[8]; uint4 v; } u;
    u.h[0]=f2bf(a.x); u.h[1]=f2bf(a.y); u.h[2]=f2bf(a.z); u.h[3]=f2bf(a.w);
    u.h[4]=f2bf(b.x); u.h[5]=f2bf(b.y); u.h[6]=f2bf(b.z); u.h[7]=f2bf(b.w);
    return u.v;
}

// tanh-form GELU (|err| ~3e-3, below bf16 quantization of He)
__device__ __forceinline__ float fast_gelu(float v) {
    float u = 0.7978845608f * v * (1.f + 0.044715f * v * v);
    float e = __expf(2.f * u);
    float t = 1.f - 2.f / (e + 1.f);
    return 0.5f * v * (1.f + t);
}

// ===== GEMM core: 128x128 block, BK=64, SINGLE-buffer 32KB LDS, 512 thr / 8 waves =====
// 16x16x32 fragments (measured 0-conflict read pattern), 4 blocks/CU = 32 waves/CU.
#define BM 128
#define BN 128
#define KSTEP 64
#define ATILE (BM*KSTEP)    // 8192 elems = 16 KiB

#define MFMA16(a,b,c) __builtin_amdgcn_mfma_f32_16x16x32_bf16(a, b, c, 0, 0, 0)

template<bool USE_STOK>
__device__ __forceinline__ void gemm1_body(u16* As, u16* Bs,
    const u16* xb, const u16* w1e, const float* b1e,
    const int* stok, int offset, int m0, int valid, int nt,
    u16* heb)
{
    int t = threadIdx.x, wid = t >> 6, lane = t & 63;
    int rl = lane >> 3, cl = lane & 7;
    int sg = cl ^ rl;                    // pre-swizzled 16B-chunk (involution on row&7)

    const u16* aP[2]; const u16* bP[2]; int dOff[2];
    #pragma unroll
    for (int c = 0; c < 2; c++) {
        int row = wid*16 + c*8 + rl;
        int ar = min(row, valid-1);
        int tok = USE_STOK ? stok[offset + m0 + ar] : (m0 + ar);
        aP[c] = xb + (size_t)tok*D_ + sg*8;
        int jg = min(nt*BN + row, H_-1);
        bP[c] = w1e + (size_t)jg*D_ + sg*8;
        dOff[c] = (wid*16 + c*8)*KSTEP;
    }

    int wm = (wid >> 2)*64, wn = (wid & 3)*32;
    int frow = lane & 15, kgrp = lane >> 4, swz = frow & 7;
    f32x4 acc[4][2] = {};

    constexpr int nIter = D_/KSTEP;      // 16
    for (int tt = 0; tt < nIter; ++tt) {
        __syncthreads();                 // previous compute done before overwrite
        int ko = tt*KSTEP;
        #pragma unroll
        for (int c = 0; c < 2; c++) {
            gload_lds16(aP[c]+ko, As + dOff[c]);
            gload_lds16(bP[c]+ko, Bs + dOff[c]);
        }
        __syncthreads();                 // drains vmcnt(0): tile ready
        __builtin_amdgcn_s_setprio(1);
        #pragma unroll
        for (int s = 0; s < 2; s++) {
            int cc = ((s*4 + kgrp) ^ swz) * 8;
            bf16x8 af[4], bf[2];
            #pragma unroll
            for (int mf = 0; mf < 4; mf++)
                af[mf] = *(const bf16x8*)&As[(wm + mf*16 + frow)*KSTEP + cc];
            #pragma unroll
            for (int nf = 0; nf < 2; nf++)
                bf[nf] = *(const bf16x8*)&Bs[(wn + nf*16 + frow)*KSTEP + cc];
            #pragma unroll
            for (int mf = 0; mf < 4; mf++)
                #pragma unroll
                for (int nf = 0; nf < 2; nf++)
                    acc[mf][nf] = MFMA16(af[mf], bf[nf], acc[mf][nf]);
        }
        __builtin_amdgcn_s_setprio(0);
    }

    int r4 = (lane >> 4)*4, cEl = lane & 15;
    #pragma unroll
    for (int nf = 0; nf < 2; nf++) {
        int gcol = nt*BN + wn + nf*16 + cEl;
        bool cok = gcol < H_;
        float bias = cok ? b1e[gcol] : 0.f;
        #pragma unroll
        for (int mf = 0; mf < 4; mf++) {
            #pragma unroll
            for (int r = 0; r < 4; r++) {
                int row = wm + mf*16 + r4 + r;
                if (row < valid) {
                    float v = 0.f;
                    if (cok) v = fast_gelu(acc[mf][nf][r] + bias);
                    heb[(size_t)(offset + m0 + row)*HP + gcol] = f2bf(v);
                }
            }
        }
    }
}

// out += w * (He @ W2e^T + b2e).  MODE 0: plain store (shared, w=1); MODE 1: atomicAdd
template<int MODE>
__device__ __forceinline__ void gemm2_body(u16* As, u16* Bs,
    const u16* heb, const u16* w2e, const float* b2e, const float* sw,
    int offset, int m0, int valid, int nt, float* out, const int* stok)
{
    int t = threadIdx.x, wid = t >> 6, lane = t & 63;
    int rl = lane >> 3, cl = lane & 7;
    int sg = cl ^ rl;

    const u16* aP[2]; const u16* bP[2]; int dOff[2];
    #pragma unroll
    for (int c = 0; c < 2; c++) {
        int row = wid*16 + c*8 + rl;
        int ar = min(row, valid-1);
        aP[c] = heb + (size_t)(offset + m0 + ar)*HP + sg*8;
        int jg = nt*BN + row;             // < 1024 always
        bP[c] = w2e + (size_t)jg*HP + sg*8;
        dOff[c] = (wid*16 + c*8)*KSTEP;
    }

    int wm = (wid >> 2)*64, wn = (wid & 3)*32;
    int frow = lane & 15, kgrp = lane >> 4, swz = frow & 7;
    f32x4 acc[4][2] = {};

    constexpr int nIter = HP/KSTEP;      // 22
    for (int tt = 0; tt < nIter; ++tt) {
        __syncthreads();
        int ko = tt*KSTEP;
        #pragma unroll
        for (int c = 0; c < 2; c++) {
            gload_lds16(aP[c]+ko, As + dOff[c]);
            gload_lds16(bP[c]+ko, Bs + dOff[c]);
        }
        __syncthreads();
        __builtin_amdgcn_s_setprio(1);
        #pragma unroll
        for (int s = 0; s < 2; s++) {
            int cc = ((s*4 + kgrp) ^ swz) * 8;
            bf16x8 af[4], bf[2];
            #pragma unroll
            for (int mf = 0; mf < 4; mf++)
                af[mf] = *(const bf16x8*)&As[(wm + mf*16 + frow)*KSTEP + cc];
            #pragma unroll
            for (int nf = 0; nf < 2; nf++)
                bf[nf] = *(const bf16x8*)&Bs[(wn + nf*16 + frow)*KSTEP + cc];
            #pragma unroll
            for (int mf = 0; mf < 4; mf++)
                #pragma unroll
                for (int nf = 0; nf < 2; nf++)
                    acc[mf][nf] = MFMA16(af[mf], bf[nf], acc[mf][nf]);
        }
        __builtin_amdgcn_s_setprio(0);
    }

    int r4 = (lane >> 4)*4, cEl = lane & 15;
    #pragma unroll
    for (int nf = 0; nf < 2; nf++) {
        int gcol = nt*BN + wn + nf*16 + cEl;
        float bias = b2e[gcol];
        #pragma unroll
        for (int mf = 0; mf < 4; mf++) {
            #pragma unroll
            for (int r = 0; r < 4; r++) {
                int row = wm + mf*16 + r4 + r;
                if (row < valid) {
                    if (MODE == 0) {
                        out[(size_t)(m0 + row)*D_ + gcol] = acc[mf][nf][r] + bias;
                    } else {
                        int slot = offset + m0 + row;
                        atomicAdd(out + (size_t)stok[slot]*D_ + gcol,
                                  sw[slot]*(acc[mf][nf][r] + bias));
                    }
                }
            }
        }
    }
}

// ================= finalize (512 threads): counts, offsets, losses, scatter =================
__device__ void finalize_body(char* big, char* small,
    const int* tidx, const float* tw, const float* probs, const float* lse2,
    int* ci, int* stok, float* sw, float* out)
{
    int*   lt   = (int*)big;                // 4096 ints (16 KiB) = all of As
    float* psum = (float*)small;            // in Bs
    float* lsum = (float*)(small + 32);
    int*   cntS = (int*)(small + 64);
    int*   offS = (int*)(small + 96);
    int t = threadIdx.x;
    if (t < 8) { psum[t] = 0.f; cntS[t] = 0; }
    if (t == 0) *lsum = 0.f;
    for (int i = t; i < NTOK*2; i += 512) lt[i] = tidx[i];
    __syncthreads();
    float lp[E_] = {}; float ll = 0.f;
    for (int n = t; n < NTOK; n += 512) {
        #pragma unroll
        for (int e = 0; e < E_; e++) lp[e] += probs[n*8+e];
        ll += lse2[n];
    }
    #pragma unroll
    for (int e = 0; e < E_; e++) atomicAdd(&psum[e], lp[e]);
    atomicAdd(lsum, ll);
    int wid = t >> 6, lane = t & 63;
    if (wid < 7) {
        int c = 0;
        for (int i = lane; i < NTOK*2; i += 64) c += (lt[i] == wid) ? 1 : 0;
        #pragma unroll
        for (int m = 32; m >= 1; m >>= 1) c += __shfl_xor(c, m);
        if (lane == 0) cntS[wid] = c;
    } else {
        for (int n = lane; n < NTOK; n += 64) {
            stok[SHARED_BASE+n] = n; sw[SHARED_BASE+n] = 1.f;
        }
    }
    __syncthreads();
    if (t == 0) {
        int o = 0;
        for (int e = 0; e < E_; e++) { offS[e] = o; o += cntS[e]; }
        offS[7] = SHARED_BASE; cntS[7] = NTOK;
        float la = 0.f;
        for (int e = 0; e < E_; e++)
            la += ((float)cntS[e] / (float)(NTOK*2)) * (psum[e] / (float)NTOK);
        out[(size_t)NTOK*D_]     = 0.01f * 7.f * la;
        out[(size_t)NTOK*D_ + 1] = 0.001f * (*lsum) / (float)NTOK;
        #pragma unroll
        for (int e = 0; e < 8; e++) { ci[CI_COUNT+e] = cntS[e]; ci[CI_OFF+e] = offS[e]; }
    }
    __syncthreads();
    if (wid < 7) {
        int base = offS[wid], run = 0;
        for (int c0 = 0; c0 < NTOK*2; c0 += 64) {
            bool m = (lt[c0 + lane] == wid);
            unsigned long long bal = __ballot(m);
            int pre = __popcll(bal & ((1ull << lane) - 1ull));
            if (m) {
                int i = c0 + lane;
                int s = base + run + pre;
                stok[s] = i >> 1; sw[s] = tw[i];
            }
            run += __popcll(bal);
        }
    }
}

// ==== k1: router (0..511) || W1 + b1 convert (512..1535) — NO LDS, full occupancy ====
__global__ void prep_kernel(
    const float* __restrict__ x, const float* __restrict__ Wg,
    const float* __restrict__ W1, const float* __restrict__ Ws1,
    const float* __restrict__ b1, const float* __restrict__ bs1,
    int* __restrict__ tidx, float* __restrict__ tw,
    float* __restrict__ probs, float* __restrict__ lse2,
    u16* __restrict__ xb, u16* __restrict__ w1b, float* __restrict__ b1all)
{
    int b = blockIdx.x;
    if (b < 512) {
        int wid = threadIdx.x >> 6, lane = threadIdx.x & 63;
        int n = b*4 + wid;
        float p[E_] = {};
        const float* xr = x + (size_t)n*D_;
        u16* xbr = xb + (size_t)n*D_;
        #pragma unroll
        for (int j = 0; j < 4; j++) {
            int d0 = lane*4 + j*256;
            float4 xv = *(const float4*)(xr + d0);
            ushort4 h;
            h.x = f2bf(xv.x); h.y = f2bf(xv.y); h.z = f2bf(xv.z); h.w = f2bf(xv.w);
            *(ushort4*)(xbr + d0) = h;
            #pragma unroll
            for (int e = 0; e < E_; e++) {
                float4 wv = *(const float4*)(Wg + e*D_ + d0);
                p[e] += xv.x*wv.x + xv.y*wv.y + xv.z*wv.z + xv.w*wv.w;
            }
        }
        #pragma unroll
        for (int e = 0; e < E_; e++) {
            float v = p[e];
            #pragma unroll
            for (int m = 32; m >= 1; m >>= 1) v += __shfl_xor(v, m);
            p[e] = v;
        }
        if (lane == 0) {
            float mx = p[0];
            #pragma unroll
            for (int e = 1; e < E_; e++) mx = fmaxf(mx, p[e]);
            float pr[E_], sum = 0.f;
            #pragma unroll
            for (int e = 0; e < E_; e++) { pr[e] = __expf(p[e]-mx); sum += pr[e]; }
            float lse = mx + logf(sum);
            int i0 = 0;
            #pragma unroll
            for (int e = 1; e < E_; e++) if (p[e] > p[i0]) i0 = e;
            int i1 = -1;
            #pragma unroll
            for (int e = 0; e < E_; e++) if (e != i0 && (i1 < 0 || p[e] > p[i1])) i1 = e;
            float g = expf(p[i1] - p[i0]);
            tidx[n*2] = i0; tidx[n*2+1] = i1;
            tw[n*2] = 1.f/(1.f+g); tw[n*2+1] = g/(1.f+g);
            float inv = 1.f/sum;
            #pragma unroll
            for (int e = 0; e < E_; e++) probs[n*8+e] = pr[e]*inv;
            lse2[n] = lse*lse;
        }
        return;
    }
    // ---- W1 (flat vectorized) + b1 biases, all 32-bit indexing ----
    const unsigned G1 = (unsigned)(NE*H_*D_/8);
    const unsigned W1FLAT = 7u*(unsigned)(H_*D_);
    const unsigned total = G1 + (unsigned)(NE*H_);
    const unsigned stride = 1024u*256u;
    for (unsigned i = (unsigned)(b-512)*256u + threadIdx.x; i < total; i += stride) {
        if (i < G1) {
            unsigned base = i*8u;
            const float* src = (base < W1FLAT) ? (W1 + base) : (Ws1 + (base - W1FLAT));
            const float4* s = (const float4*)src;
            ((uint4*)w1b)[i] = pack8(s[0], s[1]);
        } else {
            unsigned k = i - G1;
            unsigned e = k / 1365u, j = k - e*1365u;
            b1all[k] = (e < 7u) ? b1[k] : bs1[j];
        }
    }
}

// ===== k2: finalize (blk 0) || shared GEMM1 (1..176) || W2+b2 convert (177..1008) =====
__global__ __launch_bounds__(512, 8) void k2_kernel(
    const float* __restrict__ W2, const float* __restrict__ Ws2,
    const float* __restrict__ b2, const float* __restrict__ bs2,
    u16* __restrict__ w2b, float* __restrict__ b2all,
    const int* __restrict__ tidx, const float* __restrict__ tw,
    const float* __restrict__ probs, const float* __restrict__ lse2,
    int* __restrict__ ci, int* __restrict__ stok, float* __restrict__ sw,
    float* __restrict__ out,
    const u16* __restrict__ xb, const u16* __restrict__ w1b,
    const float* __restrict__ b1all, u16* __restrict__ heb)
{
    __shared__ u16 As[ATILE];
    __shared__ u16 Bs[ATILE];
    int b = blockIdx.x;
    if (b == 0) {
        finalize_body((char*)As, (char*)Bs, tidx, tw, probs, lse2, ci, stok, sw, out);
        return;
    }
    if (b <= 176) {
        int tdx = b - 1;
        int mt = tdx/11, nt = tdx - mt*11;
        gemm1_body<false>(As, Bs, xb, w1b + (size_t)7*H_*D_, b1all + 7*H_,
                          nullptr, SHARED_BASE, mt*BM, BM, nt, heb);
        return;
    }
    // ---- W2 convert: source-driven float4 groups + b2 biases + w2b pad-zero ----
    const unsigned DH  = (unsigned)(D_*H_);
    const unsigned G2v = 2u*DH;
    const unsigned BIAS = (unsigned)(NE*D_/4);
    const unsigned PAD  = (unsigned)(NE*D_)*(unsigned)(HP-H_);
    const unsigned total = G2v + BIAS + PAD;
    const unsigned stride = 832u*512u;
    for (unsigned g = (unsigned)(b-177)*512u + threadIdx.x; g < total; g += stride) {
        if (g < G2v) {
            unsigned base = g*4u;
            unsigned ec = base / DH;
            unsigned r  = base - ec*DH;
            unsigned drow = r / 1365u;
            unsigned h  = r - drow*1365u;
            const float* src = (ec < 7u) ? (W2 + base) : (Ws2 + (base - 7u*DH));
            float4 v = *(const float4*)src;
            float vv[4] = {v.x, v.y, v.z, v.w};
            u16* rb = w2b + ((size_t)ec*D_ + drow)*HP;
            if (h + 3u < 1365u) {
                #pragma unroll
                for (int q = 0; q < 4; q++) rb[h+q] = f2bf(vv[q]);
            } else {
                #pragma unroll
                for (int q = 0; q < 4; q++) {
                    unsigned hq = h + q, dr = 0;
                    if (hq >= 1365u) { hq -= 1365u; dr = 1; }
                    rb[(size_t)dr*HP + hq] = f2bf(vv[q]);
                }
            }
            continue;
        }
        unsigned k = g - G2v;
        if (k < BIAS) {
            unsigned base = k*4u;
            unsigned e = base >> 10, j = base & 1023u;
            float4 v = (e < 7u) ? *(const float4*)(b2 + base) : *(const float4*)(bs2 + j);
            *(float4*)(b2all + base) = v;
            continue;
        }
        k -= BIAS;
        unsigned row = k / 43u, j = k - row*43u;
        w2b[(size_t)row*HP + 1365u + j] = 0;
    }
}

// ===== k3: routed GEMM1 (XCD-pinned, yb<176) || shared GEMM2 (yb>=176) =====
__global__ __launch_bounds__(512, 8) void k3_kernel(
    const int* __restrict__ ci, const int* __restrict__ stok,
    const u16* __restrict__ xb, const u16* __restrict__ w1b,
    const float* __restrict__ b1all, u16* __restrict__ heb,
    const u16* __restrict__ w2b, const float* __restrict__ b2all,
    float* __restrict__ out)
{
    __shared__ u16 As[ATILE];
    __shared__ u16 Bs[ATILE];
    int x = blockIdx.x, yb = blockIdx.y;
    if (yb < 176) {
        if (x == 7) return;
        int e = x, mt = yb/11, nt = yb - mt*11;
        int count = ci[CI_COUNT+e];
        int m0 = mt*BM;
        if (m0 >= count) return;
        gemm1_body<true>(As, Bs, xb, w1b + (size_t)e*H_*D_, b1all + e*H_,
                         stok, ci[CI_OFF+e], m0, min(BM, count-m0), nt, heb);
    } else {
        int idx = (yb - 176)*8 + x;       // 0..127
        int mt = idx >> 3, nt = idx & 7;
        gemm2_body<0>(As, Bs, heb, w2b + (size_t)7*D_*HP, b2all + 7*D_,
                      nullptr, SHARED_BASE, mt*BM, BM, nt, out, nullptr);
    }
}

// ===== k4: routed GEMM2 (XCD-pinned), atomicAdd into out =====
__global__ __launch_bounds__(512, 8) void k4_kernel(
    const int* __restrict__ ci, const int* __restrict__ stok, const float* __restrict__ sw,
    const u16* __restrict__ heb, const u16* __restrict__ w2b,
    const float* __restrict__ b2all, float* __restrict__ out)
{
    __shared__ u16 As[ATILE];
    __shared__ u16 Bs[ATILE];
    int x = blockIdx.x;
    if (x == 7) return;
    int yb = blockIdx.y;
    int e = x, mt = yb >> 3, nt = yb & 7;
    int count = ci[CI_COUNT+e];
    int m0 = mt*BM;
    if (m0 >= count) return;
    gemm2_body<1>(As, Bs, heb, w2b + (size_t)e*D_*HP, b2all + e*D_,
                  sw, ci[CI_OFF+e], m0, min(BM, count-m0), nt, out, stok);
}

extern "C" void kernel_launch(void* const* d_in, const int* in_sizes, int n_in,
                              void* d_out, int out_size, void* d_ws, size_t ws_size,
                              hipStream_t stream)
{
    const float* x   = (const float*)d_in[0];
    const float* Wg  = (const float*)d_in[1];
    const float* W1  = (const float*)d_in[2];
    const float* b1  = (const float*)d_in[3];
    const float* W2  = (const float*)d_in[4];
    const float* b2  = (const float*)d_in[5];
    const float* Ws1 = (const float*)d_in[6];
    const float* bs1 = (const float*)d_in[7];
    const float* Ws2 = (const float*)d_in[8];
    const float* bs2 = (const float*)d_in[9];
    float* out = (float*)d_out;
    char* ws = (char*)d_ws;

    int*   ci    = (int*)(ws + WS_CTRL);
    int*   tidx  = (int*)(ws + WS_TIDX);
    float* tw    = (float*)(ws + WS_TW);
    float* probs = (float*)(ws + WS_PROB);
    float* lse2  = (float*)(ws + WS_LSE2);
    int*   stok  = (int*)(ws + WS_STOK);
    float* sw    = (float*)(ws + WS_SW);
    float* b1all = (float*)(ws + WS_B1);
    float* b2all = (float*)(ws + WS_B2);
    u16*   xb    = (u16*)(ws + WS_XB);
    u16*   w1b   = (u16*)(ws + WS_W1B);
    u16*   w2b   = (u16*)(ws + WS_W2B);
    u16*   heb   = (u16*)(ws + WS_HEB);

    // k1: router (512) || W1 + b1 convert (1024) — zero LDS, full occupancy
    prep_kernel<<<1536, 256, 0, stream>>>(x, Wg, W1, Ws1, b1, bs1,
                                          tidx, tw, probs, lse2, xb, w1b, b1all);
    // k2: finalize || shared GEMM1 (176) || W2 + b2 convert (832)
    k2_kernel<<<1009, 512, 0, stream>>>(W2, Ws2, b2, bs2, w2b, b2all,
                                        tidx, tw, probs, lse2, ci, stok, sw, out,
                                        xb, w1b, b1all, heb);
    // k3: routed GEMM1 (expert->XCD pinned) || shared GEMM2
    k3_kernel<<<dim3(8, 176 + 16), 512, 0, stream>>>(ci, stok, xb, w1b, b1all, heb,
                                                     w2b, b2all, out);
    // k4: routed GEMM2, weighted atomic accumulate
    k4_kernel<<<dim3(8, 128), 512, 0, stream>>>(ci, stok, sw, heb, w2b, b2all, out);
}